// Round 8
// baseline (525.868 us; speedup 1.0000x reference)
//
#include <hip/hip_runtime.h>

#define NCFG 8
#define NN 100000
#define NE 400000
#define NG 10
#define FEAT 97
#define SCAN_BLOCKS 25   // ceil(NN/4096)

typedef __attribute__((ext_vector_type(8))) short bf16x8;
typedef __attribute__((ext_vector_type(4))) short bf16x4;
typedef __attribute__((ext_vector_type(4))) float f32x4;

__device__ inline short f2bf(float x){
  unsigned u = __float_as_uint(x);
  unsigned r = u + 0x7FFFu + ((u >> 16) & 1u);
  return (short)(r >> 16);
}
__device__ inline float bf2f(short h){
  return __uint_as_float(((unsigned)(unsigned short)h) << 16);
}

// ---------------- CSR build ----------------
__global__ void k_hist(const int* __restrict__ src, int* __restrict__ deg, int e_count){
  int e = blockIdx.x*blockDim.x + threadIdx.x;
  if(e < e_count) atomicAdd(&deg[src[e]], 1);
}

__global__ __launch_bounds__(1024) void k_scanA(const int* __restrict__ deg,
    int* __restrict__ partial, int n){
  __shared__ int ws[16];
  int tid = threadIdx.x;
  int i0 = blockIdx.x*4096 + tid*4;
  int s = 0;
  #pragma unroll
  for(int i=0;i<4;i++) if(i0+i < n) s += deg[i0+i];
  #pragma unroll
  for(int off=1; off<64; off<<=1) s += __shfl_xor(s, off, 64);
  if((tid & 63) == 0) ws[tid >> 6] = s;
  __syncthreads();
  if(tid < 16){
    int v = ws[tid];
    #pragma unroll
    for(int off=1; off<16; off<<=1) v += __shfl_xor(v, off, 16);
    if(tid == 0) partial[blockIdx.x] = v;
  }
}

__global__ void k_scanB(int* __restrict__ partial, int* __restrict__ rowptr, int nb, int n){
  int tid = threadIdx.x;   // 64
  int v = (tid < nb) ? partial[tid] : 0;
  int x = v;
  #pragma unroll
  for(int off=1; off<64; off<<=1){
    int t = __shfl_up(x, off, 64);
    if(tid >= off) x += t;
  }
  if(tid < nb) partial[tid] = x - v;
  if(tid == nb-1) rowptr[n] = x;
}

__global__ __launch_bounds__(1024) void k_scanC(int* __restrict__ deg_cur,
    const int* __restrict__ partial, int* __restrict__ rowptr,
    float* __restrict__ inv_deg, int n){
  __shared__ int wsum[16];
  int tid = threadIdx.x, lane = tid & 63, w = tid >> 6;
  int i0 = blockIdx.x*4096 + tid*4;
  int v0 = (i0+0 < n) ? deg_cur[i0+0] : 0;
  int v1 = (i0+1 < n) ? deg_cur[i0+1] : 0;
  int v2 = (i0+2 < n) ? deg_cur[i0+2] : 0;
  int v3 = (i0+3 < n) ? deg_cur[i0+3] : 0;
  int s = v0+v1+v2+v3;
  int x = s;
  #pragma unroll
  for(int off=1; off<64; off<<=1){
    int t = __shfl_up(x, off, 64);
    if(lane >= off) x += t;
  }
  if(lane == 63) wsum[w] = x;
  __syncthreads();
  if(w == 0){
    int y = (lane < 16) ? wsum[lane] : 0;
    #pragma unroll
    for(int off=1; off<16; off<<=1){
      int t = __shfl_up(y, off, 64);
      if(lane >= off) y += t;
    }
    if(lane < 16) wsum[lane] = y;
  }
  __syncthreads();
  int waveoff = (w > 0) ? wsum[w-1] : 0;
  int run = partial[blockIdx.x] + waveoff + (x - s);
  if(i0+0 < n){ rowptr[i0+0]=run; deg_cur[i0+0]=run; inv_deg[i0+0]=1.0f/(float)max(v0,1); run+=v0; }
  if(i0+1 < n){ rowptr[i0+1]=run; deg_cur[i0+1]=run; inv_deg[i0+1]=1.0f/(float)max(v1,1); run+=v1; }
  if(i0+2 < n){ rowptr[i0+2]=run; deg_cur[i0+2]=run; inv_deg[i0+2]=1.0f/(float)max(v2,1); run+=v2; }
  if(i0+3 < n){ rowptr[i0+3]=run; deg_cur[i0+3]=run; inv_deg[i0+3]=1.0f/(float)max(v3,1); run+=v3; }
}

__global__ void k_fill(const int* __restrict__ src, const int* __restrict__ dst,
                       int* __restrict__ cursor, int* __restrict__ col, int e_count){
  int e = blockIdx.x*blockDim.x + threadIdx.x;
  if(e < e_count){
    int pos = atomicAdd(&cursor[src[e]], 1);
    col[pos] = dst[e];
  }
}

// ---------------- fused prep: embW1 | B-fragments | graph offsets ----------------
__global__ __launch_bounds__(256) void k_prep(const float* __restrict__ emb,
    const float* __restrict__ W1, const float* __restrict__ W2,
    const int* __restrict__ lengths, float* __restrict__ embW1,
    short* __restrict__ bW1hi, short* __restrict__ bW1lo,
    short* __restrict__ bW2hi, short* __restrict__ bW2lo, int* __restrict__ goff){
  int b = blockIdx.x, tid = threadIdx.x;
  if(b < 128){
    if(tid < 64){
      float s = 0.f;
      #pragma unroll
      for(int k=0;k<32;k++) s += emb[b*32+k] * W1[k*64+tid];
      embW1[b*64+tid] = s;
    }
  } else if(b < 152){
    int e = (b-128)*256 + tid;          // 0..6143
    {
      int i=e&7, l=(e>>3)&63, t=(e>>9)&3, kc=e>>11;
      int k=kc*32+((l>>4)<<3)+i, c=t*16+(l&15);
      float wv = W1[(32+k)*64+c];
      short h=f2bf(wv); bW1hi[e]=h; bW1lo[e]=f2bf(wv-bf2f(h));
    }
    if(e < 4096){
      int i=e&7, l=(e>>3)&63, t=(e>>9)&3, kc=e>>11;
      int k=kc*32+((l>>4)<<3)+i, c=t*16+(l&15);
      float wv = W2[k*64+c];
      short h=f2bf(wv); bW2hi[e]=h; bW2lo[e]=f2bf(wv-bf2f(h));
    }
  } else {
    if(tid == 0){
      int s = 0;
      for(int g=0; g<NG; g++){ goff[g] = s; s += lengths[g]; }
      goff[NG] = s;
    }
  }
}

// ---------------- gemm1 (MFMA, swapped): 4 cfgs per block, reg-staged prefetch ----------------
// z layout per pass: [node][4cfg][64] bf16
__global__ __launch_bounds__(256) void k_gemm1(const float* __restrict__ feat,
    const float* __restrict__ embW1,
    const short* __restrict__ bW1hi, const short* __restrict__ bW1lo,
    unsigned short* __restrict__ z_all, int c0){
  __shared__ float lds_f[64*FEAT];      // 24832 B, [row][97]
  int tid = threadIdx.x;
  int nb = blockIdx.x * 64;
  int w = tid >> 6, l = tid & 63;
  int node_loc = w*16 + (l & 15);
  int g = l >> 4;
  int g8 = g << 3;
  bool full = (nb + 64 <= NN);

  float4 st[7];
  #define LOADREGS(c) { \
    const float* gp = feat + ((size_t)(c)*NN + nb)*FEAT; \
    _Pragma("unroll") \
    for(int i=0;i<6;i++) st[i] = *(const float4*)(gp + (tid + i*256)*4); \
    if(tid < 16) st[6] = *(const float4*)(gp + (tid + 1536)*4); \
  }
  #define WRITELDS() { \
    _Pragma("unroll") \
    for(int i=0;i<6;i++) *(float4*)&lds_f[(tid + i*256)*4] = st[i]; \
    if(tid < 16) *(float4*)&lds_f[(tid + 1536)*4] = st[6]; \
  }

  if(full) LOADREGS(c0);

  for(int cc = 0; cc < 4; cc++){
    __syncthreads();                    // LDS free (prev compute done)
    if(full){
      WRITELDS();
      if(cc < 3) LOADREGS(c0+cc+1);     // issue next-cfg loads early (overlap with MFMA)
    } else {
      const float* gp = feat + ((size_t)(c0+cc)*NN + nb)*FEAT;
      int nvalid = (NN - nb)*FEAT;
      for(int idx = tid; idx < 1552; idx += 256){
        int base = idx*4;
        float4 v;
        v.x = (base+0 < nvalid) ? gp[base+0] : 0.f;
        v.y = (base+1 < nvalid) ? gp[base+1] : 0.f;
        v.z = (base+2 < nvalid) ? gp[base+2] : 0.f;
        v.w = (base+3 < nvalid) ? gp[base+3] : 0.f;
        *(float4*)&lds_f[base] = v;
      }
    }
    __syncthreads();

    f32x4 acc[4] = {{0,0,0,0},{0,0,0,0},{0,0,0,0},{0,0,0,0}};
    #pragma unroll
    for(int kc = 0; kc < 3; kc++){
      const float* ap = &lds_f[node_loc*FEAT + 1 + g8 + kc*32];
      bf16x8 bfeat;
      #pragma unroll
      for(int i=0;i<8;i++) bfeat[i] = f2bf(ap[i]);
      #pragma unroll
      for(int t=0;t<4;t++){
        const bf16x8 ah = *(const bf16x8*)&bW1hi[((kc*4 + t)*64 + l)*8];
        const bf16x8 al = *(const bf16x8*)&bW1lo[((kc*4 + t)*64 + l)*8];
        acc[t] = __builtin_amdgcn_mfma_f32_16x16x32_bf16(ah, bfeat, acc[t], 0,0,0);
        acc[t] = __builtin_amdgcn_mfma_f32_16x16x32_bf16(al, bfeat, acc[t], 0,0,0);
      }
    }
    int node = nb + node_loc;
    if(node < NN){
      int op = (int)lds_f[node_loc*FEAT];
      unsigned short* zrow = z_all + ((size_t)node*4 + cc)*64;
      #pragma unroll
      for(int t=0;t<4;t++){
        int f0 = t*16 + g*4;
        const float4 e = *(const float4*)&embW1[op*64 + f0];
        ushort4 pk;
        pk.x = (unsigned short)f2bf(acc[t][0] + e.x);
        pk.y = (unsigned short)f2bf(acc[t][1] + e.y);
        pk.z = (unsigned short)f2bf(acc[t][2] + e.z);
        pk.w = (unsigned short)f2bf(acc[t][3] + e.w);
        *(ushort4*)(zrow + f0) = pk;
      }
    }
  }
  #undef LOADREGS
  #undef WRITELDS
}

// ---------------- gather1: h[n][cc][*] = relu(inv*sum_nb z[nb][cc][*] + b1) ----------------
// wave per node, 512B payload: lane = cc*16+sub owns 4 cols (8B)
__global__ __launch_bounds__(256) void k_gather1(const int* __restrict__ rowptr,
    const int* __restrict__ col, const float* __restrict__ inv_deg,
    const unsigned short* __restrict__ z_all, const float* __restrict__ b1,
    unsigned short* __restrict__ h_all){
  int tid = threadIdx.x, lane = tid & 63;
  int n = (blockIdx.x << 2) + (tid >> 6);
  if(n >= NN) return;
  int sub = lane & 15;
  const unsigned short* zl = z_all + lane*4;
  int kb = rowptr[n], ke = rowptr[n+1];
  float a0[4]={0,0,0,0}, a1[4]={0,0,0,0}, a2[4]={0,0,0,0}, a3[4]={0,0,0,0};
  int k = kb;
  for(; k+4 <= ke; k += 4){
    int d0=col[k], d1=col[k+1], d2=col[k+2], d3=col[k+3];
    const bf16x4 v0 = *(const bf16x4*)(zl + (size_t)d0*256);
    const bf16x4 v1 = *(const bf16x4*)(zl + (size_t)d1*256);
    const bf16x4 v2 = *(const bf16x4*)(zl + (size_t)d2*256);
    const bf16x4 v3 = *(const bf16x4*)(zl + (size_t)d3*256);
    #pragma unroll
    for(int i=0;i<4;i++){
      a0[i] += bf2f(v0[i]); a1[i] += bf2f(v1[i]);
      a2[i] += bf2f(v2[i]); a3[i] += bf2f(v3[i]);
    }
  }
  for(; k < ke; k++){
    int d = col[k];
    const bf16x4 v = *(const bf16x4*)(zl + (size_t)d*256);
    #pragma unroll
    for(int i=0;i<4;i++) a0[i] += bf2f(v[i]);
  }
  float inv = inv_deg[n];
  const float4 b = *(const float4*)(b1 + sub*4);
  float bv[4] = {b.x,b.y,b.z,b.w};
  bf16x4 o;
  #pragma unroll
  for(int i=0;i<4;i++){
    float acc = (a0[i]+a1[i]) + (a2[i]+a3[i]);
    o[i] = f2bf(fmaxf(fmaf(acc, inv, bv[i]), 0.f));
  }
  *(bf16x4*)(h_all + (size_t)n*256 + lane*4) = o;
}

// ---------------- gather2W: r = |relu((mean_agg h) @ W2 + b2) . Wp + bp| ----------------
// block = 16 nodes x 4 cfg = 64 V rows; phase1 agg -> LDS, phase2 MFMA + epilogue
__global__ __launch_bounds__(256) void k_gather2W(const int* __restrict__ rowptr,
    const int* __restrict__ col, const float* __restrict__ inv_deg,
    const unsigned short* __restrict__ h_all,
    const short* __restrict__ bW2hi, const short* __restrict__ bW2lo,
    const float* __restrict__ b2, const float* __restrict__ Wp,
    const float* __restrict__ bp, float* __restrict__ r_all, int c0){
  __shared__ unsigned short V[64][68];   // row = node_local*4 + cc
  int tid = threadIdx.x, lane = tid & 63, w = tid >> 6;
  int nb = blockIdx.x * 16;
  int cc = lane >> 4, sub = lane & 15;
  const unsigned short* hl = h_all + lane*4;

  for(int i = 0; i < 4; i++){
    int nl = w*4 + i;
    int n = nb + nl;
    int kb = rowptr[n], ke = rowptr[n+1];
    float a0[4]={0,0,0,0}, a1[4]={0,0,0,0}, a2[4]={0,0,0,0}, a3[4]={0,0,0,0};
    int k = kb;
    for(; k+4 <= ke; k += 4){
      int d0=col[k], d1=col[k+1], d2=col[k+2], d3=col[k+3];
      const bf16x4 v0 = *(const bf16x4*)(hl + (size_t)d0*256);
      const bf16x4 v1 = *(const bf16x4*)(hl + (size_t)d1*256);
      const bf16x4 v2 = *(const bf16x4*)(hl + (size_t)d2*256);
      const bf16x4 v3 = *(const bf16x4*)(hl + (size_t)d3*256);
      #pragma unroll
      for(int j=0;j<4;j++){
        a0[j] += bf2f(v0[j]); a1[j] += bf2f(v1[j]);
        a2[j] += bf2f(v2[j]); a3[j] += bf2f(v3[j]);
      }
    }
    for(; k < ke; k++){
      int d = col[k];
      const bf16x4 v = *(const bf16x4*)(hl + (size_t)d*256);
      #pragma unroll
      for(int j=0;j<4;j++) a0[j] += bf2f(v[j]);
    }
    float inv = inv_deg[n];
    bf16x4 o;
    #pragma unroll
    for(int j=0;j<4;j++){
      float acc = (a0[j]+a1[j]) + (a2[j]+a3[j]);
      o[j] = f2bf(acc * inv);
    }
    *(bf16x4*)&V[nl*4 + cc][sub*4] = o;
  }
  __syncthreads();

  // phase 2: wave w owns V rows w*16..w*16+15
  float bp0 = bp[0];
  int cb = lane & 15;
  int koff = (lane >> 4) << 3;
  int trow = w*16 + cb;
  f32x4 acc[4] = {{0,0,0,0},{0,0,0,0},{0,0,0,0},{0,0,0,0}};
  #pragma unroll
  for(int kc = 0; kc < 2; kc++){
    const bf16x8 a = *(const bf16x8*)&V[trow][kc*32 + koff];
    #pragma unroll
    for(int t=0;t<4;t++){
      const bf16x8 bh = *(const bf16x8*)&bW2hi[((kc*4+t)*64 + lane)*8];
      const bf16x8 bl = *(const bf16x8*)&bW2lo[((kc*4+t)*64 + lane)*8];
      acc[t] = __builtin_amdgcn_mfma_f32_16x16x32_bf16(a, bh, acc[t], 0,0,0);
      acc[t] = __builtin_amdgcn_mfma_f32_16x16x32_bf16(a, bl, acc[t], 0,0,0);
    }
  }
  float part[4];
  #pragma unroll
  for(int j=0;j<4;j++){
    float p = 0.f;
    #pragma unroll
    for(int t=0;t<4;t++){
      int c = t*16 + cb;
      p += fmaxf(acc[t][j] + b2[c], 0.f) * Wp[c];
    }
    part[j] = p;
  }
  #pragma unroll
  for(int off=1; off<16; off<<=1){
    #pragma unroll
    for(int j=0;j<4;j++) part[j] += __shfl_xor(part[j], off, 64);
  }
  if(cb == 0){
    #pragma unroll
    for(int j=0;j<4;j++){
      int row = w*16 + ((lane>>4)<<2) + j;   // 0..63
      int node = nb + (row >> 2);
      int cfgo = c0 + (row & 3);
      r_all[(size_t)cfgo*NN + node] = fabsf(part[j] + bp0);
    }
  }
}

// ---------------- pool ----------------
__global__ __launch_bounds__(256) void k_pool(const float* __restrict__ r_all,
    const int* __restrict__ off, float* __restrict__ out){
  __shared__ float red[256];
  int b = blockIdx.x;               // b = g*8 + c
  int g = b >> 3, c = b & 7;
  int lo = off[g], hi = off[g+1];
  float s = 0.f;
  for(int i = lo + (int)threadIdx.x; i < hi; i += 256) s += r_all[(size_t)c*NN + i];
  red[threadIdx.x] = s;
  __syncthreads();
  for(int w=128; w>0; w>>=1){
    if((int)threadIdx.x < w) red[threadIdx.x] += red[threadIdx.x + w];
    __syncthreads();
  }
  if(threadIdx.x == 0) out[b] = red[0];
}

extern "C" void kernel_launch(void* const* d_in, const int* in_sizes, int n_in,
                              void* d_out, int out_size, void* d_ws, size_t ws_size,
                              hipStream_t stream){
  (void)in_sizes; (void)n_in; (void)out_size; (void)ws_size;
  const float* feat = (const float*)d_in[0];
  const int*   eidx = (const int*)d_in[1];
  const int*   lens = (const int*)d_in[2];
  const float* emb  = (const float*)d_in[3];
  const float* W1   = (const float*)d_in[4];
  const float* b1   = (const float*)d_in[5];
  const float* W2   = (const float*)d_in[6];
  const float* b2   = (const float*)d_in[7];
  const float* Wp   = (const float*)d_in[8];
  const float* bp   = (const float*)d_in[9];
  float* out = (float*)d_out;
  const int* src = eidx;
  const int* dst = eidx + NE;

  char* ws = (char*)d_ws;
  size_t o = 0;
  auto alloc = [&](size_t bytes)->char*{ char* p = ws + o; o = (o + bytes + 255) & ~(size_t)255; return p; };
  int*   rowptr  = (int*)  alloc((NN+1)*4);
  int*   cursor  = (int*)  alloc((size_t)NN*4);
  int*   colx    = (int*)  alloc((size_t)NE*4);
  float* invd    = (float*)alloc((size_t)NN*4);
  int*   goff    = (int*)  alloc((NG+1)*4);
  int*   spart   = (int*)  alloc(SCAN_BLOCKS*4);
  float* eW1     = (float*)alloc(128*64*4);
  short* bW1hi   = (short*)alloc(3*4*64*8*2);
  short* bW1lo   = (short*)alloc(3*4*64*8*2);
  short* bW2hi   = (short*)alloc(2*4*64*8*2);
  short* bW2lo   = (short*)alloc(2*4*64*8*2);
  float* r_all   = (float*)alloc((size_t)NCFG*NN*4);
  unsigned short* z_all = (unsigned short*)alloc((size_t)NN*4*64*2);  // 51.2 MB, [node][4cfg][64]
  unsigned short* h_all = (unsigned short*)alloc((size_t)NN*4*64*2);  // 51.2 MB

  hipMemsetAsync(cursor, 0, (size_t)NN*4, stream);
  k_hist  <<<(NE+255)/256, 256, 0, stream>>>(src, cursor, NE);
  k_scanA <<<SCAN_BLOCKS, 1024, 0, stream>>>(cursor, spart, NN);
  k_scanB <<<1, 64, 0, stream>>>(spart, rowptr, SCAN_BLOCKS, NN);
  k_scanC <<<SCAN_BLOCKS, 1024, 0, stream>>>(cursor, spart, rowptr, invd, NN);
  k_fill  <<<(NE+255)/256, 256, 0, stream>>>(src, dst, cursor, colx, NE);
  k_prep  <<<153, 256, 0, stream>>>(emb, W1, W2, lens, eW1, bW1hi, bW1lo, bW2hi, bW2lo, goff);

  for(int c0 = 0; c0 < NCFG; c0 += 4){
    k_gemm1   <<<(NN+63)/64, 256, 0, stream>>>(feat, eW1, bW1hi, bW1lo, z_all, c0);
    k_gather1 <<<(NN+3)/4, 256, 0, stream>>>(rowptr, colx, invd, z_all, b1, h_all);
    k_gather2W<<<NN/16, 256, 0, stream>>>(rowptr, colx, invd, h_all, bW2hi, bW2lo, b2, Wp, bp, r_all, c0);
  }
  k_pool<<<NCFG*NG, 256, 0, stream>>>(r_all, goff, out);
}

// Round 9
// 370.128 us; speedup vs baseline: 1.4208x; 1.4208x over previous
//
#include <hip/hip_runtime.h>

#define NCFG 8
#define NN 100000
#define NE 400000
#define NG 10
#define FEAT 97
#define SCAN_BLOCKS 25   // ceil(NN/4096)

typedef __attribute__((ext_vector_type(8))) short bf16x8;
typedef __attribute__((ext_vector_type(4))) float f32x4;

__device__ inline short f2bf(float x){
  unsigned u = __float_as_uint(x);
  unsigned r = u + 0x7FFFu + ((u >> 16) & 1u);
  return (short)(r >> 16);
}
__device__ inline float bf2f(short h){
  return __uint_as_float(((unsigned)(unsigned short)h) << 16);
}

// ---------------- CSR build ----------------
__global__ void k_hist(const int* __restrict__ src, int* __restrict__ deg, int e_count){
  int e = blockIdx.x*blockDim.x + threadIdx.x;
  if(e < e_count) atomicAdd(&deg[src[e]], 1);
}

__global__ __launch_bounds__(1024) void k_scanA(const int* __restrict__ deg,
    int* __restrict__ partial, int n){
  __shared__ int ws[16];
  int tid = threadIdx.x;
  int i0 = blockIdx.x*4096 + tid*4;
  int s = 0;
  #pragma unroll
  for(int i=0;i<4;i++) if(i0+i < n) s += deg[i0+i];
  #pragma unroll
  for(int off=1; off<64; off<<=1) s += __shfl_xor(s, off, 64);
  if((tid & 63) == 0) ws[tid >> 6] = s;
  __syncthreads();
  if(tid < 16){
    int v = ws[tid];
    #pragma unroll
    for(int off=1; off<16; off<<=1) v += __shfl_xor(v, off, 16);
    if(tid == 0) partial[blockIdx.x] = v;
  }
}

// local scan + inline prefix of partials (scanB folded in)
__global__ __launch_bounds__(1024) void k_scanC(int* __restrict__ deg_cur,
    const int* __restrict__ partial, int* __restrict__ rowptr,
    float* __restrict__ inv_deg, int n){
  __shared__ int wsum[16];
  __shared__ int s2[2];            // [0]=block offset, [1]=grand total
  int tid = threadIdx.x, lane = tid & 63, w = tid >> 6;
  if(tid < 64){
    int pv  = (lane < SCAN_BLOCKS) ? partial[lane] : 0;
    int pre = (lane < (int)blockIdx.x) ? pv : 0;
    #pragma unroll
    for(int off=1; off<32; off<<=1){
      pv  += __shfl_xor(pv,  off, 64);
      pre += __shfl_xor(pre, off, 64);
    }
    if(lane == 0){ s2[0] = pre; s2[1] = pv; }
  }
  int i0 = blockIdx.x*4096 + tid*4;
  int v0 = (i0+0 < n) ? deg_cur[i0+0] : 0;
  int v1 = (i0+1 < n) ? deg_cur[i0+1] : 0;
  int v2 = (i0+2 < n) ? deg_cur[i0+2] : 0;
  int v3 = (i0+3 < n) ? deg_cur[i0+3] : 0;
  int s = v0+v1+v2+v3;
  int x = s;
  #pragma unroll
  for(int off=1; off<64; off<<=1){
    int t = __shfl_up(x, off, 64);
    if(lane >= off) x += t;
  }
  if(lane == 63) wsum[w] = x;
  __syncthreads();
  if(w == 0){
    int y = (lane < 16) ? wsum[lane] : 0;
    #pragma unroll
    for(int off=1; off<16; off<<=1){
      int t = __shfl_up(y, off, 64);
      if(lane >= off) y += t;
    }
    if(lane < 16) wsum[lane] = y;
  }
  __syncthreads();
  int waveoff = (w > 0) ? wsum[w-1] : 0;
  int run = s2[0] + waveoff + (x - s);
  if(i0+0 < n){ rowptr[i0+0]=run; deg_cur[i0+0]=run; inv_deg[i0+0]=1.0f/(float)max(v0,1); run+=v0; }
  if(i0+1 < n){ rowptr[i0+1]=run; deg_cur[i0+1]=run; inv_deg[i0+1]=1.0f/(float)max(v1,1); run+=v1; }
  if(i0+2 < n){ rowptr[i0+2]=run; deg_cur[i0+2]=run; inv_deg[i0+2]=1.0f/(float)max(v2,1); run+=v2; }
  if(i0+3 < n){ rowptr[i0+3]=run; deg_cur[i0+3]=run; inv_deg[i0+3]=1.0f/(float)max(v3,1); run+=v3; }
  if(blockIdx.x == gridDim.x-1 && tid == 0) rowptr[n] = s2[1];
}

__global__ void k_fill(const int* __restrict__ src, const int* __restrict__ dst,
                       int* __restrict__ cursor, int* __restrict__ col, int e_count){
  int e = blockIdx.x*blockDim.x + threadIdx.x;
  if(e < e_count){
    int pos = atomicAdd(&cursor[src[e]], 1);
    col[pos] = dst[e];
  }
}

// ---------------- fused prep: embW1 | B-fragments | graph offsets ----------------
__global__ __launch_bounds__(256) void k_prep(const float* __restrict__ emb,
    const float* __restrict__ W1, const float* __restrict__ W2,
    const int* __restrict__ lengths, float* __restrict__ embW1,
    short* __restrict__ bW1hi, short* __restrict__ bW1lo,
    short* __restrict__ bW2hi, short* __restrict__ bW2lo, int* __restrict__ goff){
  int b = blockIdx.x, tid = threadIdx.x;
  if(b < 128){
    if(tid < 64){
      float s = 0.f;
      #pragma unroll
      for(int k=0;k<32;k++) s += emb[b*32+k] * W1[k*64+tid];
      embW1[b*64+tid] = s;
    }
  } else if(b < 152){
    int e = (b-128)*256 + tid;          // 0..6143
    {
      int i=e&7, l=(e>>3)&63, t=(e>>9)&3, kc=e>>11;
      int k=kc*32+((l>>4)<<3)+i, c=t*16+(l&15);
      float wv = W1[(32+k)*64+c];
      short h=f2bf(wv); bW1hi[e]=h; bW1lo[e]=f2bf(wv-bf2f(h));
    }
    if(e < 4096){
      int i=e&7, l=(e>>3)&63, t=(e>>9)&3, kc=e>>11;
      int k=kc*32+((l>>4)<<3)+i, c=t*16+(l&15);
      float wv = W2[k*64+c];
      short h=f2bf(wv); bW2hi[e]=h; bW2lo[e]=f2bf(wv-bf2f(h));
    }
  } else {
    if(tid == 0){
      int s = 0;
      for(int g=0; g<NG; g++){ goff[g] = s; s += lengths[g]; }
      goff[NG] = s;
    }
  }
}

// ---------------- gemm1 (MFMA, swapped) + LDS-transpose coalesced stores ----------------
// z layout: [node][cfg][64] bf16 (8-cfg row = 1KB contiguous for gathers)
__global__ __launch_bounds__(256) void k_gemm1(const float* __restrict__ feat,
    const float* __restrict__ embW1,
    const short* __restrict__ bW1hi, const short* __restrict__ bW1lo,
    unsigned short* __restrict__ z_all){
  __shared__ float lds_f[64*FEAT];      // 24832 B; reused as zt[64][68] bf16 in epilogue
  int tid = threadIdx.x;
  int nb = blockIdx.x * 64;
  int cfg = blockIdx.y;
  const float* gsrc = feat + ((size_t)cfg*NN + nb)*FEAT;

  if(nb + 64 <= NN){
    for(int idx = tid; idx < 1552; idx += 256)
      *(float4*)&lds_f[idx*4] = *(const float4*)(gsrc + idx*4);
  } else {
    int nvalid = (NN - nb)*FEAT;
    for(int idx = tid; idx < 1552; idx += 256){
      int base = idx*4;
      float4 v;
      v.x = (base+0 < nvalid) ? gsrc[base+0] : 0.f;
      v.y = (base+1 < nvalid) ? gsrc[base+1] : 0.f;
      v.z = (base+2 < nvalid) ? gsrc[base+2] : 0.f;
      v.w = (base+3 < nvalid) ? gsrc[base+3] : 0.f;
      *(float4*)&lds_f[base] = v;
    }
  }
  __syncthreads();

  int w = tid >> 6, l = tid & 63;
  int node_loc = w*16 + (l & 15);
  int g = l >> 4;
  int g8 = g << 3;

  f32x4 acc[4] = {{0,0,0,0},{0,0,0,0},{0,0,0,0},{0,0,0,0}};
  #pragma unroll
  for(int kc = 0; kc < 3; kc++){
    const float* ap = &lds_f[node_loc*FEAT + 1 + g8 + kc*32];
    bf16x8 bfeat;
    #pragma unroll
    for(int i=0;i<8;i++) bfeat[i] = f2bf(ap[i]);
    #pragma unroll
    for(int t=0;t<4;t++){
      const bf16x8 ah = *(const bf16x8*)&bW1hi[((kc*4 + t)*64 + l)*8];
      const bf16x8 al = *(const bf16x8*)&bW1lo[((kc*4 + t)*64 + l)*8];
      acc[t] = __builtin_amdgcn_mfma_f32_16x16x32_bf16(ah, bfeat, acc[t], 0,0,0);
      acc[t] = __builtin_amdgcn_mfma_f32_16x16x32_bf16(al, bfeat, acc[t], 0,0,0);
    }
  }
  // lane's 16 results: features t*16+g*4..+3 of node node_loc
  int myop = (int)lds_f[node_loc*FEAT];
  __syncthreads();                      // all lds_f reads done; reuse as zt
  unsigned short* zt = (unsigned short*)lds_f;   // [64][68]
  #pragma unroll
  for(int t=0;t<4;t++){
    int f0 = t*16 + (g<<2);
    const float4 e = *(const float4*)&embW1[myop*64 + f0];
    ushort4 pk;
    pk.x = (unsigned short)f2bf(acc[t][0] + e.x);
    pk.y = (unsigned short)f2bf(acc[t][1] + e.y);
    pk.z = (unsigned short)f2bf(acc[t][2] + e.z);
    pk.w = (unsigned short)f2bf(acc[t][3] + e.w);
    *(ushort4*)&zt[node_loc*68 + f0] = pk;
  }
  __syncthreads();
  // coalesced store: 64 rows x 128B; per instruction 16 threads cover one row
  unsigned short* zbase = z_all + ((size_t)nb*NCFG + cfg)*64;
  #pragma unroll
  for(int it = 0; it < 4; it++){
    int idx = it*256 + tid;             // 0..1023
    int row = idx >> 4;
    int cg  = (idx & 15) << 2;          // ushort offset (8B chunks)
    if(nb + row < NN)
      *(uint2*)(zbase + (size_t)row*NCFG*64 + cg) = *(const uint2*)&zt[row*68 + cg];
  }
}

// ---------------- gather1: h[n][c] = relu(inv*sum_nb z[nb][c] + b1), 4-chain ILP ----------------
__global__ __launch_bounds__(256) void k_gather1(const int* __restrict__ rowptr,
    const int* __restrict__ col, const float* __restrict__ inv_deg,
    const unsigned short* __restrict__ z_all, const float* __restrict__ b1,
    unsigned short* __restrict__ h_all){
  int tid = threadIdx.x, lane = tid & 63;
  int n = (blockIdx.x << 2) + (tid >> 6);
  if(n >= NN) return;
  int sub = lane & 7;
  const unsigned short* zl = z_all + lane*8;
  int kb = rowptr[n], ke = rowptr[n+1];
  float a0[8]={0,0,0,0,0,0,0,0}, a1[8]={0,0,0,0,0,0,0,0};
  float a2[8]={0,0,0,0,0,0,0,0}, a3[8]={0,0,0,0,0,0,0,0};
  int k = kb;
  for(; k+4 <= ke; k += 4){
    int d0=col[k], d1=col[k+1], d2=col[k+2], d3=col[k+3];
    const bf16x8 v0 = *(const bf16x8*)(zl + (size_t)d0*512);
    const bf16x8 v1 = *(const bf16x8*)(zl + (size_t)d1*512);
    const bf16x8 v2 = *(const bf16x8*)(zl + (size_t)d2*512);
    const bf16x8 v3 = *(const bf16x8*)(zl + (size_t)d3*512);
    #pragma unroll
    for(int i=0;i<8;i++){
      a0[i] += bf2f(v0[i]); a1[i] += bf2f(v1[i]);
      a2[i] += bf2f(v2[i]); a3[i] += bf2f(v3[i]);
    }
  }
  for(; k < ke; k++){
    int d = col[k];
    const bf16x8 v = *(const bf16x8*)(zl + (size_t)d*512);
    #pragma unroll
    for(int i=0;i<8;i++) a0[i] += bf2f(v[i]);
  }
  float inv = inv_deg[n];
  const float4 bA = *(const float4*)(b1 + sub*8);
  const float4 bB = *(const float4*)(b1 + sub*8 + 4);
  float bv[8] = {bA.x,bA.y,bA.z,bA.w,bB.x,bB.y,bB.z,bB.w};
  bf16x8 o;
  #pragma unroll
  for(int i=0;i<8;i++){
    float acc = (a0[i]+a1[i]) + (a2[i]+a3[i]);
    o[i] = f2bf(fmaxf(fmaf(acc, inv, bv[i]), 0.f));
  }
  *(bf16x8*)(h_all + (size_t)n*512 + lane*8) = o;
}

// ---------------- gather2W: r = |relu((mean_agg h) @ W2 + b2) . Wp + bp| ----------------
__global__ __launch_bounds__(256) void k_gather2W(const int* __restrict__ rowptr,
    const int* __restrict__ col, const float* __restrict__ inv_deg,
    const unsigned short* __restrict__ h_all,
    const short* __restrict__ bW2hi, const short* __restrict__ bW2lo,
    const float* __restrict__ b2, const float* __restrict__ Wp,
    const float* __restrict__ bp, float* __restrict__ r_all){
  __shared__ unsigned short V[128][68];   // row = node_local*8 + cfg
  int tid = threadIdx.x, lane = tid & 63, w = tid >> 6;
  int nb = blockIdx.x * 16;
  int cfg = lane >> 3, sub = lane & 7;
  const unsigned short* hl = h_all + lane*8;

  for(int i = 0; i < 4; i++){
    int nl = w*4 + i;
    int n = nb + nl;
    int kb = rowptr[n], ke = rowptr[n+1];
    float a0[8]={0,0,0,0,0,0,0,0}, a1[8]={0,0,0,0,0,0,0,0};
    float a2[8]={0,0,0,0,0,0,0,0}, a3[8]={0,0,0,0,0,0,0,0};
    int k = kb;
    for(; k+4 <= ke; k += 4){
      int d0=col[k], d1=col[k+1], d2=col[k+2], d3=col[k+3];
      const bf16x8 v0 = *(const bf16x8*)(hl + (size_t)d0*512);
      const bf16x8 v1 = *(const bf16x8*)(hl + (size_t)d1*512);
      const bf16x8 v2 = *(const bf16x8*)(hl + (size_t)d2*512);
      const bf16x8 v3 = *(const bf16x8*)(hl + (size_t)d3*512);
      #pragma unroll
      for(int j=0;j<8;j++){
        a0[j] += bf2f(v0[j]); a1[j] += bf2f(v1[j]);
        a2[j] += bf2f(v2[j]); a3[j] += bf2f(v3[j]);
      }
    }
    for(; k < ke; k++){
      int d = col[k];
      const bf16x8 v = *(const bf16x8*)(hl + (size_t)d*512);
      #pragma unroll
      for(int j=0;j<8;j++) a0[j] += bf2f(v[j]);
    }
    float inv = inv_deg[n];
    bf16x8 o;
    #pragma unroll
    for(int j=0;j<8;j++){
      float acc = (a0[j]+a1[j]) + (a2[j]+a3[j]);
      o[j] = f2bf(acc * inv);
    }
    *(bf16x8*)&V[nl*8 + cfg][sub*8] = o;
  }
  __syncthreads();

  float bp0 = bp[0];
  int cb = lane & 15;
  int koff = (lane >> 4) << 3;
  #pragma unroll
  for(int at = 0; at < 2; at++){
    int tile = w*2 + at;                 // 0..7
    int trow = tile*16 + cb;
    f32x4 acc[4] = {{0,0,0,0},{0,0,0,0},{0,0,0,0},{0,0,0,0}};
    #pragma unroll
    for(int kc = 0; kc < 2; kc++){
      const bf16x8 a = *(const bf16x8*)&V[trow][kc*32 + koff];
      #pragma unroll
      for(int t=0;t<4;t++){
        const bf16x8 bh = *(const bf16x8*)&bW2hi[((kc*4+t)*64 + lane)*8];
        const bf16x8 bl = *(const bf16x8*)&bW2lo[((kc*4+t)*64 + lane)*8];
        acc[t] = __builtin_amdgcn_mfma_f32_16x16x32_bf16(a, bh, acc[t], 0,0,0);
        acc[t] = __builtin_amdgcn_mfma_f32_16x16x32_bf16(a, bl, acc[t], 0,0,0);
      }
    }
    float part[4];
    #pragma unroll
    for(int j=0;j<4;j++){
      float p = 0.f;
      #pragma unroll
      for(int t=0;t<4;t++){
        int c = t*16 + cb;
        p += fmaxf(acc[t][j] + b2[c], 0.f) * Wp[c];
      }
      part[j] = p;
    }
    #pragma unroll
    for(int off=1; off<16; off<<=1){
      #pragma unroll
      for(int j=0;j<4;j++) part[j] += __shfl_xor(part[j], off, 64);
    }
    if(cb == 0){
      #pragma unroll
      for(int j=0;j<4;j++){
        int row = tile*16 + ((lane>>4)<<2) + j;   // 0..127 within block
        int node = nb + (row >> 3);
        int cfgo = row & 7;
        r_all[(size_t)cfgo*NN + node] = fabsf(part[j] + bp0);
      }
    }
  }
}

// ---------------- pool ----------------
__global__ __launch_bounds__(256) void k_pool(const float* __restrict__ r_all,
    const int* __restrict__ off, float* __restrict__ out){
  __shared__ float red[256];
  int b = blockIdx.x;               // b = g*8 + c
  int g = b >> 3, c = b & 7;
  int lo = off[g], hi = off[g+1];
  float s = 0.f;
  for(int i = lo + (int)threadIdx.x; i < hi; i += 256) s += r_all[(size_t)c*NN + i];
  red[threadIdx.x] = s;
  __syncthreads();
  for(int w=128; w>0; w>>=1){
    if((int)threadIdx.x < w) red[threadIdx.x] += red[threadIdx.x + w];
    __syncthreads();
  }
  if(threadIdx.x == 0) out[b] = red[0];
}

extern "C" void kernel_launch(void* const* d_in, const int* in_sizes, int n_in,
                              void* d_out, int out_size, void* d_ws, size_t ws_size,
                              hipStream_t stream){
  (void)in_sizes; (void)n_in; (void)out_size; (void)ws_size;
  const float* feat = (const float*)d_in[0];
  const int*   eidx = (const int*)d_in[1];
  const int*   lens = (const int*)d_in[2];
  const float* emb  = (const float*)d_in[3];
  const float* W1   = (const float*)d_in[4];
  const float* b1   = (const float*)d_in[5];
  const float* W2   = (const float*)d_in[6];
  const float* b2   = (const float*)d_in[7];
  const float* Wp   = (const float*)d_in[8];
  const float* bp   = (const float*)d_in[9];
  float* out = (float*)d_out;
  const int* src = eidx;
  const int* dst = eidx + NE;

  char* ws = (char*)d_ws;
  size_t o = 0;
  auto alloc = [&](size_t bytes)->char*{ char* p = ws + o; o = (o + bytes + 255) & ~(size_t)255; return p; };
  int*   rowptr  = (int*)  alloc((NN+1)*4);
  int*   cursor  = (int*)  alloc((size_t)NN*4);
  int*   colx    = (int*)  alloc((size_t)NE*4);
  float* invd    = (float*)alloc((size_t)NN*4);
  int*   goff    = (int*)  alloc((NG+1)*4);
  int*   spart   = (int*)  alloc(SCAN_BLOCKS*4);
  float* eW1     = (float*)alloc(128*64*4);
  short* bW1hi   = (short*)alloc(3*4*64*8*2);
  short* bW1lo   = (short*)alloc(3*4*64*8*2);
  short* bW2hi   = (short*)alloc(2*4*64*8*2);
  short* bW2lo   = (short*)alloc(2*4*64*8*2);
  float* r_all   = (float*)alloc((size_t)NCFG*NN*4);
  unsigned short* z_all = (unsigned short*)alloc((size_t)NN*NCFG*64*2);  // 102.4 MB, [node][cfg][64]
  unsigned short* h_all = (unsigned short*)alloc((size_t)NN*NCFG*64*2);  // 102.4 MB

  hipMemsetAsync(cursor, 0, (size_t)NN*4, stream);
  k_hist  <<<(NE+255)/256, 256, 0, stream>>>(src, cursor, NE);
  k_scanA <<<SCAN_BLOCKS, 1024, 0, stream>>>(cursor, spart, NN);
  k_scanC <<<SCAN_BLOCKS, 1024, 0, stream>>>(cursor, spart, rowptr, invd, NN);
  k_fill  <<<(NE+255)/256, 256, 0, stream>>>(src, dst, cursor, colx, NE);
  k_prep  <<<153, 256, 0, stream>>>(emb, W1, W2, lens, eW1, bW1hi, bW1lo, bW2hi, bW2lo, goff);

  dim3 ggemm((NN+63)/64, NCFG);
  k_gemm1   <<<ggemm, 256, 0, stream>>>(feat, eW1, bW1hi, bW1lo, z_all);
  k_gather1 <<<(NN+3)/4, 256, 0, stream>>>(rowptr, colx, invd, z_all, b1, h_all);
  k_gather2W<<<NN/16, 256, 0, stream>>>(rowptr, colx, invd, h_all, bW2hi, bW2lo, b2, Wp, bp, r_all);
  k_pool<<<NCFG*NG, 256, 0, stream>>>(r_all, goff, out);
}

// Round 10
// 357.796 us; speedup vs baseline: 1.4697x; 1.0345x over previous
//
#include <hip/hip_runtime.h>

#define NCFG 8
#define NN 100000
#define NE 400000
#define NG 10
#define FEAT 97
#define SCAN_BLOCKS 25   // ceil(NN/4096)

typedef __attribute__((ext_vector_type(8))) short bf16x8;
typedef __attribute__((ext_vector_type(4))) float f32x4;

__device__ inline short f2bf(float x){
  unsigned u = __float_as_uint(x);
  unsigned r = u + 0x7FFFu + ((u >> 16) & 1u);
  return (short)(r >> 16);
}
__device__ inline float bf2f(short h){
  return __uint_as_float(((unsigned)(unsigned short)h) << 16);
}

// ---------------- CSR build ----------------
__global__ void k_hist(const int* __restrict__ src, int* __restrict__ deg, int e_count){
  int e = blockIdx.x*blockDim.x + threadIdx.x;
  if(e < e_count) atomicAdd(&deg[src[e]], 1);
}

__global__ __launch_bounds__(1024) void k_scanA(const int* __restrict__ deg,
    int* __restrict__ partial, int n){
  __shared__ int ws[16];
  int tid = threadIdx.x;
  int i0 = blockIdx.x*4096 + tid*4;
  int s = 0;
  #pragma unroll
  for(int i=0;i<4;i++) if(i0+i < n) s += deg[i0+i];
  #pragma unroll
  for(int off=1; off<64; off<<=1) s += __shfl_xor(s, off, 64);
  if((tid & 63) == 0) ws[tid >> 6] = s;
  __syncthreads();
  if(tid < 16){
    int v = ws[tid];
    #pragma unroll
    for(int off=1; off<16; off<<=1) v += __shfl_xor(v, off, 16);
    if(tid == 0) partial[blockIdx.x] = v;
  }
}

// local scan + inline prefix of partials (scanB folded in)
__global__ __launch_bounds__(1024) void k_scanC(int* __restrict__ deg_cur,
    const int* __restrict__ partial, int* __restrict__ rowptr,
    float* __restrict__ inv_deg, int n){
  __shared__ int wsum[16];
  __shared__ int s2[2];            // [0]=block offset, [1]=grand total
  int tid = threadIdx.x, lane = tid & 63, w = tid >> 6;
  if(tid < 64){
    int pv  = (lane < SCAN_BLOCKS) ? partial[lane] : 0;
    int pre = (lane < (int)blockIdx.x) ? pv : 0;
    #pragma unroll
    for(int off=1; off<32; off<<=1){
      pv  += __shfl_xor(pv,  off, 64);
      pre += __shfl_xor(pre, off, 64);
    }
    if(lane == 0){ s2[0] = pre; s2[1] = pv; }
  }
  int i0 = blockIdx.x*4096 + tid*4;
  int v0 = (i0+0 < n) ? deg_cur[i0+0] : 0;
  int v1 = (i0+1 < n) ? deg_cur[i0+1] : 0;
  int v2 = (i0+2 < n) ? deg_cur[i0+2] : 0;
  int v3 = (i0+3 < n) ? deg_cur[i0+3] : 0;
  int s = v0+v1+v2+v3;
  int x = s;
  #pragma unroll
  for(int off=1; off<64; off<<=1){
    int t = __shfl_up(x, off, 64);
    if(lane >= off) x += t;
  }
  if(lane == 63) wsum[w] = x;
  __syncthreads();
  if(w == 0){
    int y = (lane < 16) ? wsum[lane] : 0;
    #pragma unroll
    for(int off=1; off<16; off<<=1){
      int t = __shfl_up(y, off, 64);
      if(lane >= off) y += t;
    }
    if(lane < 16) wsum[lane] = y;
  }
  __syncthreads();
  int waveoff = (w > 0) ? wsum[w-1] : 0;
  int run = s2[0] + waveoff + (x - s);
  if(i0+0 < n){ rowptr[i0+0]=run; deg_cur[i0+0]=run; inv_deg[i0+0]=1.0f/(float)max(v0,1); run+=v0; }
  if(i0+1 < n){ rowptr[i0+1]=run; deg_cur[i0+1]=run; inv_deg[i0+1]=1.0f/(float)max(v1,1); run+=v1; }
  if(i0+2 < n){ rowptr[i0+2]=run; deg_cur[i0+2]=run; inv_deg[i0+2]=1.0f/(float)max(v2,1); run+=v2; }
  if(i0+3 < n){ rowptr[i0+3]=run; deg_cur[i0+3]=run; inv_deg[i0+3]=1.0f/(float)max(v3,1); run+=v3; }
  if(blockIdx.x == gridDim.x-1 && tid == 0) rowptr[n] = s2[1];
}

__global__ void k_fill(const int* __restrict__ src, const int* __restrict__ dst,
                       int* __restrict__ cursor, int* __restrict__ col, int e_count){
  int e = blockIdx.x*blockDim.x + threadIdx.x;
  if(e < e_count){
    int pos = atomicAdd(&cursor[src[e]], 1);
    col[pos] = dst[e];
  }
}

// ---------------- fused prep: embW1 | B-fragments | graph offsets ----------------
__global__ __launch_bounds__(256) void k_prep(const float* __restrict__ emb,
    const float* __restrict__ W1, const float* __restrict__ W2,
    const int* __restrict__ lengths, float* __restrict__ embW1,
    short* __restrict__ bW1hi, short* __restrict__ bW1lo,
    short* __restrict__ bW2hi, short* __restrict__ bW2lo, int* __restrict__ goff){
  int b = blockIdx.x, tid = threadIdx.x;
  if(b < 128){
    if(tid < 64){
      float s = 0.f;
      #pragma unroll
      for(int k=0;k<32;k++) s += emb[b*32+k] * W1[k*64+tid];
      embW1[b*64+tid] = s;
    }
  } else if(b < 152){
    int e = (b-128)*256 + tid;          // 0..6143
    {
      int i=e&7, l=(e>>3)&63, t=(e>>9)&3, kc=e>>11;
      int k=kc*32+((l>>4)<<3)+i, c=t*16+(l&15);
      float wv = W1[(32+k)*64+c];
      short h=f2bf(wv); bW1hi[e]=h; bW1lo[e]=f2bf(wv-bf2f(h));
    }
    if(e < 4096){
      int i=e&7, l=(e>>3)&63, t=(e>>9)&3, kc=e>>11;
      int k=kc*32+((l>>4)<<3)+i, c=t*16+(l&15);
      float wv = W2[k*64+c];
      short h=f2bf(wv); bW2hi[e]=h; bW2lo[e]=f2bf(wv-bf2f(h));
    }
  } else {
    if(tid == 0){
      int s = 0;
      for(int g=0; g<NG; g++){ goff[g] = s; s += lengths[g]; }
      goff[NG] = s;
    }
  }
}

// ---------------- gemm1 (MFMA, swapped) — feat via NT loads (no L3 allocation) ----------------
// z layout: [node][cfg][64] bf16
__global__ __launch_bounds__(256) void k_gemm1(const float* __restrict__ feat,
    const float* __restrict__ embW1,
    const short* __restrict__ bW1hi, const short* __restrict__ bW1lo,
    unsigned short* __restrict__ z_all){
  __shared__ float lds_f[64*FEAT];      // 24832 B; reused as zt[64][68] bf16 in epilogue
  int tid = threadIdx.x;
  int nb = blockIdx.x * 64;
  int cfg = blockIdx.y;
  const float* gsrc = feat + ((size_t)cfg*NN + nb)*FEAT;

  if(nb + 64 <= NN){
    for(int idx = tid; idx < 1552; idx += 256){
      f32x4 v = __builtin_nontemporal_load((const f32x4*)(gsrc + idx*4));
      *(f32x4*)&lds_f[idx*4] = v;
    }
  } else {
    int nvalid = (NN - nb)*FEAT;
    for(int idx = tid; idx < 1552; idx += 256){
      int base = idx*4;
      float4 v;
      v.x = (base+0 < nvalid) ? __builtin_nontemporal_load(gsrc + base+0) : 0.f;
      v.y = (base+1 < nvalid) ? __builtin_nontemporal_load(gsrc + base+1) : 0.f;
      v.z = (base+2 < nvalid) ? __builtin_nontemporal_load(gsrc + base+2) : 0.f;
      v.w = (base+3 < nvalid) ? __builtin_nontemporal_load(gsrc + base+3) : 0.f;
      *(float4*)&lds_f[base] = v;
    }
  }
  __syncthreads();

  int w = tid >> 6, l = tid & 63;
  int node_loc = w*16 + (l & 15);
  int g = l >> 4;
  int g8 = g << 3;

  f32x4 acc[4] = {{0,0,0,0},{0,0,0,0},{0,0,0,0},{0,0,0,0}};
  #pragma unroll
  for(int kc = 0; kc < 3; kc++){
    const float* ap = &lds_f[node_loc*FEAT + 1 + g8 + kc*32];
    bf16x8 bfeat;
    #pragma unroll
    for(int i=0;i<8;i++) bfeat[i] = f2bf(ap[i]);
    #pragma unroll
    for(int t=0;t<4;t++){
      const bf16x8 ah = *(const bf16x8*)&bW1hi[((kc*4 + t)*64 + l)*8];
      const bf16x8 al = *(const bf16x8*)&bW1lo[((kc*4 + t)*64 + l)*8];
      acc[t] = __builtin_amdgcn_mfma_f32_16x16x32_bf16(ah, bfeat, acc[t], 0,0,0);
      acc[t] = __builtin_amdgcn_mfma_f32_16x16x32_bf16(al, bfeat, acc[t], 0,0,0);
    }
  }
  // lane's 16 results: features t*16+g*4..+3 of node node_loc
  int myop = (int)lds_f[node_loc*FEAT];
  __syncthreads();                      // all lds_f reads done; reuse as zt
  unsigned short* zt = (unsigned short*)lds_f;   // [64][68]
  #pragma unroll
  for(int t=0;t<4;t++){
    int f0 = t*16 + (g<<2);
    const float4 e = *(const float4*)&embW1[myop*64 + f0];
    ushort4 pk;
    pk.x = (unsigned short)f2bf(acc[t][0] + e.x);
    pk.y = (unsigned short)f2bf(acc[t][1] + e.y);
    pk.z = (unsigned short)f2bf(acc[t][2] + e.z);
    pk.w = (unsigned short)f2bf(acc[t][3] + e.w);
    *(ushort4*)&zt[node_loc*68 + f0] = pk;
  }
  __syncthreads();
  // coalesced store: 64 rows x 128B (normal caching — gather1 reuses z 4x)
  unsigned short* zbase = z_all + ((size_t)nb*NCFG + cfg)*64;
  #pragma unroll
  for(int it = 0; it < 4; it++){
    int idx = it*256 + tid;             // 0..1023
    int row = idx >> 4;
    int cg  = (idx & 15) << 2;          // ushort offset (8B chunks)
    if(nb + row < NN)
      *(uint2*)(zbase + (size_t)row*NCFG*64 + cg) = *(const uint2*)&zt[row*68 + cg];
  }
}

// ---------------- gather1: h[n][c] = relu(inv*sum_nb z[nb][c] + b1), 4-chain ILP ----------------
__global__ __launch_bounds__(256) void k_gather1(const int* __restrict__ rowptr,
    const int* __restrict__ col, const float* __restrict__ inv_deg,
    const unsigned short* __restrict__ z_all, const float* __restrict__ b1,
    unsigned short* __restrict__ h_all){
  int tid = threadIdx.x, lane = tid & 63;
  int n = (blockIdx.x << 2) + (tid >> 6);
  if(n >= NN) return;
  int sub = lane & 7;
  const unsigned short* zl = z_all + lane*8;
  int kb = rowptr[n], ke = rowptr[n+1];
  float a0[8]={0,0,0,0,0,0,0,0}, a1[8]={0,0,0,0,0,0,0,0};
  float a2[8]={0,0,0,0,0,0,0,0}, a3[8]={0,0,0,0,0,0,0,0};
  int k = kb;
  for(; k+4 <= ke; k += 4){
    int d0=col[k], d1=col[k+1], d2=col[k+2], d3=col[k+3];
    const bf16x8 v0 = *(const bf16x8*)(zl + (size_t)d0*512);
    const bf16x8 v1 = *(const bf16x8*)(zl + (size_t)d1*512);
    const bf16x8 v2 = *(const bf16x8*)(zl + (size_t)d2*512);
    const bf16x8 v3 = *(const bf16x8*)(zl + (size_t)d3*512);
    #pragma unroll
    for(int i=0;i<8;i++){
      a0[i] += bf2f(v0[i]); a1[i] += bf2f(v1[i]);
      a2[i] += bf2f(v2[i]); a3[i] += bf2f(v3[i]);
    }
  }
  for(; k < ke; k++){
    int d = col[k];
    const bf16x8 v = *(const bf16x8*)(zl + (size_t)d*512);
    #pragma unroll
    for(int i=0;i<8;i++) a0[i] += bf2f(v[i]);
  }
  float inv = inv_deg[n];
  const float4 bA = *(const float4*)(b1 + sub*8);
  const float4 bB = *(const float4*)(b1 + sub*8 + 4);
  float bv[8] = {bA.x,bA.y,bA.z,bA.w,bB.x,bB.y,bB.z,bB.w};
  bf16x8 o;
  #pragma unroll
  for(int i=0;i<8;i++){
    float acc = (a0[i]+a1[i]) + (a2[i]+a3[i]);
    o[i] = f2bf(fmaxf(fmaf(acc, inv, bv[i]), 0.f));
  }
  *(bf16x8*)(h_all + (size_t)n*512 + lane*8) = o;
}

// ---------------- gather2W: r = |relu((mean_agg h) @ W2 + b2) . Wp + bp| ----------------
__global__ __launch_bounds__(256) void k_gather2W(const int* __restrict__ rowptr,
    const int* __restrict__ col, const float* __restrict__ inv_deg,
    const unsigned short* __restrict__ h_all,
    const short* __restrict__ bW2hi, const short* __restrict__ bW2lo,
    const float* __restrict__ b2, const float* __restrict__ Wp,
    const float* __restrict__ bp, float* __restrict__ r_all){
  __shared__ unsigned short V[128][68];   // row = node_local*8 + cfg
  int tid = threadIdx.x, lane = tid & 63, w = tid >> 6;
  int nb = blockIdx.x * 16;
  int cfg = lane >> 3, sub = lane & 7;
  const unsigned short* hl = h_all + lane*8;

  for(int i = 0; i < 4; i++){
    int nl = w*4 + i;
    int n = nb + nl;
    int kb = rowptr[n], ke = rowptr[n+1];
    float a0[8]={0,0,0,0,0,0,0,0}, a1[8]={0,0,0,0,0,0,0,0};
    float a2[8]={0,0,0,0,0,0,0,0}, a3[8]={0,0,0,0,0,0,0,0};
    int k = kb;
    for(; k+4 <= ke; k += 4){
      int d0=col[k], d1=col[k+1], d2=col[k+2], d3=col[k+3];
      const bf16x8 v0 = *(const bf16x8*)(hl + (size_t)d0*512);
      const bf16x8 v1 = *(const bf16x8*)(hl + (size_t)d1*512);
      const bf16x8 v2 = *(const bf16x8*)(hl + (size_t)d2*512);
      const bf16x8 v3 = *(const bf16x8*)(hl + (size_t)d3*512);
      #pragma unroll
      for(int j=0;j<8;j++){
        a0[j] += bf2f(v0[j]); a1[j] += bf2f(v1[j]);
        a2[j] += bf2f(v2[j]); a3[j] += bf2f(v3[j]);
      }
    }
    for(; k < ke; k++){
      int d = col[k];
      const bf16x8 v = *(const bf16x8*)(hl + (size_t)d*512);
      #pragma unroll
      for(int j=0;j<8;j++) a0[j] += bf2f(v[j]);
    }
    float inv = inv_deg[n];
    bf16x8 o;
    #pragma unroll
    for(int j=0;j<8;j++){
      float acc = (a0[j]+a1[j]) + (a2[j]+a3[j]);
      o[j] = f2bf(acc * inv);
    }
    *(bf16x8*)&V[nl*8 + cfg][sub*8] = o;
  }
  __syncthreads();

  float bp0 = bp[0];
  int cb = lane & 15;
  int koff = (lane >> 4) << 3;
  #pragma unroll
  for(int at = 0; at < 2; at++){
    int tile = w*2 + at;                 // 0..7
    int trow = tile*16 + cb;
    f32x4 acc[4] = {{0,0,0,0},{0,0,0,0},{0,0,0,0},{0,0,0,0}};
    #pragma unroll
    for(int kc = 0; kc < 2; kc++){
      const bf16x8 a = *(const bf16x8*)&V[trow][kc*32 + koff];
      #pragma unroll
      for(int t=0;t<4;t++){
        const bf16x8 bh = *(const bf16x8*)&bW2hi[((kc*4+t)*64 + lane)*8];
        const bf16x8 bl = *(const bf16x8*)&bW2lo[((kc*4+t)*64 + lane)*8];
        acc[t] = __builtin_amdgcn_mfma_f32_16x16x32_bf16(a, bh, acc[t], 0,0,0);
        acc[t] = __builtin_amdgcn_mfma_f32_16x16x32_bf16(a, bl, acc[t], 0,0,0);
      }
    }
    float part[4];
    #pragma unroll
    for(int j=0;j<4;j++){
      float p = 0.f;
      #pragma unroll
      for(int t=0;t<4;t++){
        int c = t*16 + cb;
        p += fmaxf(acc[t][j] + b2[c], 0.f) * Wp[c];
      }
      part[j] = p;
    }
    #pragma unroll
    for(int off=1; off<16; off<<=1){
      #pragma unroll
      for(int j=0;j<4;j++) part[j] += __shfl_xor(part[j], off, 64);
    }
    if(cb == 0){
      #pragma unroll
      for(int j=0;j<4;j++){
        int row = tile*16 + ((lane>>4)<<2) + j;   // 0..127 within block
        int node = nb + (row >> 3);
        int cfgo = row & 7;
        r_all[(size_t)cfgo*NN + node] = fabsf(part[j] + bp0);
      }
    }
  }
}

// ---------------- pool ----------------
__global__ __launch_bounds__(256) void k_pool(const float* __restrict__ r_all,
    const int* __restrict__ off, float* __restrict__ out){
  __shared__ float red[256];
  int b = blockIdx.x;               // b = g*8 + c
  int g = b >> 3, c = b & 7;
  int lo = off[g], hi = off[g+1];
  float s = 0.f;
  for(int i = lo + (int)threadIdx.x; i < hi; i += 256) s += r_all[(size_t)c*NN + i];
  red[threadIdx.x] = s;
  __syncthreads();
  for(int w=128; w>0; w>>=1){
    if((int)threadIdx.x < w) red[threadIdx.x] += red[threadIdx.x + w];
    __syncthreads();
  }
  if(threadIdx.x == 0) out[b] = red[0];
}

extern "C" void kernel_launch(void* const* d_in, const int* in_sizes, int n_in,
                              void* d_out, int out_size, void* d_ws, size_t ws_size,
                              hipStream_t stream){
  (void)in_sizes; (void)n_in; (void)out_size; (void)ws_size;
  const float* feat = (const float*)d_in[0];
  const int*   eidx = (const int*)d_in[1];
  const int*   lens = (const int*)d_in[2];
  const float* emb  = (const float*)d_in[3];
  const float* W1   = (const float*)d_in[4];
  const float* b1   = (const float*)d_in[5];
  const float* W2   = (const float*)d_in[6];
  const float* b2   = (const float*)d_in[7];
  const float* Wp   = (const float*)d_in[8];
  const float* bp   = (const float*)d_in[9];
  float* out = (float*)d_out;
  const int* src = eidx;
  const int* dst = eidx + NE;

  char* ws = (char*)d_ws;
  size_t o = 0;
  auto alloc = [&](size_t bytes)->char*{ char* p = ws + o; o = (o + bytes + 255) & ~(size_t)255; return p; };
  int*   rowptr  = (int*)  alloc((NN+1)*4);
  int*   cursor  = (int*)  alloc((size_t)NN*4);
  int*   colx    = (int*)  alloc((size_t)NE*4);
  float* invd    = (float*)alloc((size_t)NN*4);
  int*   goff    = (int*)  alloc((NG+1)*4);
  int*   spart   = (int*)  alloc(SCAN_BLOCKS*4);
  float* eW1     = (float*)alloc(128*64*4);
  short* bW1hi   = (short*)alloc(3*4*64*8*2);
  short* bW1lo   = (short*)alloc(3*4*64*8*2);
  short* bW2hi   = (short*)alloc(2*4*64*8*2);
  short* bW2lo   = (short*)alloc(2*4*64*8*2);
  float* r_all   = (float*)alloc((size_t)NCFG*NN*4);
  unsigned short* z_all = (unsigned short*)alloc((size_t)NN*NCFG*64*2);  // 102.4 MB, [node][cfg][64]
  unsigned short* h_all = (unsigned short*)alloc((size_t)NN*NCFG*64*2);  // 102.4 MB

  hipMemsetAsync(cursor, 0, (size_t)NN*4, stream);
  k_hist  <<<(NE+255)/256, 256, 0, stream>>>(src, cursor, NE);
  k_scanA <<<SCAN_BLOCKS, 1024, 0, stream>>>(cursor, spart, NN);
  k_scanC <<<SCAN_BLOCKS, 1024, 0, stream>>>(cursor, spart, rowptr, invd, NN);
  k_fill  <<<(NE+255)/256, 256, 0, stream>>>(src, dst, cursor, colx, NE);
  k_prep  <<<153, 256, 0, stream>>>(emb, W1, W2, lens, eW1, bW1hi, bW1lo, bW2hi, bW2lo, goff);

  dim3 ggemm((NN+63)/64, NCFG);
  k_gemm1   <<<ggemm, 256, 0, stream>>>(feat, eW1, bW1hi, bW1lo, z_all);
  k_gather1 <<<(NN+3)/4, 256, 0, stream>>>(rowptr, colx, invd, z_all, b1, h_all);
  k_gather2W<<<NN/16, 256, 0, stream>>>(rowptr, colx, invd, h_all, bW2hi, bW2lo, b2, Wp, bp, r_all);
  k_pool<<<NCFG*NG, 256, 0, stream>>>(r_all, goff, out);
}

// Round 11
// 357.368 us; speedup vs baseline: 1.4715x; 1.0012x over previous
//
#include <hip/hip_runtime.h>

#define NCFG 8
#define NN 100000
#define NE 400000
#define NG 10
#define FEAT 97
#define SCAN_BLOCKS 25   // ceil(NN/4096)

typedef __attribute__((ext_vector_type(8))) short bf16x8;
typedef __attribute__((ext_vector_type(4))) float f32x4;

__device__ inline short f2bf(float x){
  unsigned u = __float_as_uint(x);
  unsigned r = u + 0x7FFFu + ((u >> 16) & 1u);
  return (short)(r >> 16);
}
__device__ inline float bf2f(short h){
  return __uint_as_float(((unsigned)(unsigned short)h) << 16);
}

// ---------------- CSR build ----------------
__global__ void k_hist(const int* __restrict__ src, int* __restrict__ deg, int e_count){
  int e = blockIdx.x*blockDim.x + threadIdx.x;
  if(e < e_count) atomicAdd(&deg[src[e]], 1);
}

__global__ __launch_bounds__(1024) void k_scanA(const int* __restrict__ deg,
    int* __restrict__ partial, int n){
  __shared__ int ws[16];
  int tid = threadIdx.x;
  int i0 = blockIdx.x*4096 + tid*4;
  int s = 0;
  #pragma unroll
  for(int i=0;i<4;i++) if(i0+i < n) s += deg[i0+i];
  #pragma unroll
  for(int off=1; off<64; off<<=1) s += __shfl_xor(s, off, 64);
  if((tid & 63) == 0) ws[tid >> 6] = s;
  __syncthreads();
  if(tid < 16){
    int v = ws[tid];
    #pragma unroll
    for(int off=1; off<16; off<<=1) v += __shfl_xor(v, off, 16);
    if(tid == 0) partial[blockIdx.x] = v;
  }
}

// local scan + inline prefix of partials (scanB folded in)
__global__ __launch_bounds__(1024) void k_scanC(int* __restrict__ deg_cur,
    const int* __restrict__ partial, int* __restrict__ rowptr,
    float* __restrict__ inv_deg, int n){
  __shared__ int wsum[16];
  __shared__ int s2[2];            // [0]=block offset, [1]=grand total
  int tid = threadIdx.x, lane = tid & 63, w = tid >> 6;
  if(tid < 64){
    int pv  = (lane < SCAN_BLOCKS) ? partial[lane] : 0;
    int pre = (lane < (int)blockIdx.x) ? pv : 0;
    #pragma unroll
    for(int off=1; off<32; off<<=1){
      pv  += __shfl_xor(pv,  off, 64);
      pre += __shfl_xor(pre, off, 64);
    }
    if(lane == 0){ s2[0] = pre; s2[1] = pv; }
  }
  int i0 = blockIdx.x*4096 + tid*4;
  int v0 = (i0+0 < n) ? deg_cur[i0+0] : 0;
  int v1 = (i0+1 < n) ? deg_cur[i0+1] : 0;
  int v2 = (i0+2 < n) ? deg_cur[i0+2] : 0;
  int v3 = (i0+3 < n) ? deg_cur[i0+3] : 0;
  int s = v0+v1+v2+v3;
  int x = s;
  #pragma unroll
  for(int off=1; off<64; off<<=1){
    int t = __shfl_up(x, off, 64);
    if(lane >= off) x += t;
  }
  if(lane == 63) wsum[w] = x;
  __syncthreads();
  if(w == 0){
    int y = (lane < 16) ? wsum[lane] : 0;
    #pragma unroll
    for(int off=1; off<16; off<<=1){
      int t = __shfl_up(y, off, 64);
      if(lane >= off) y += t;
    }
    if(lane < 16) wsum[lane] = y;
  }
  __syncthreads();
  int waveoff = (w > 0) ? wsum[w-1] : 0;
  int run = s2[0] + waveoff + (x - s);
  if(i0+0 < n){ rowptr[i0+0]=run; deg_cur[i0+0]=run; inv_deg[i0+0]=1.0f/(float)max(v0,1); run+=v0; }
  if(i0+1 < n){ rowptr[i0+1]=run; deg_cur[i0+1]=run; inv_deg[i0+1]=1.0f/(float)max(v1,1); run+=v1; }
  if(i0+2 < n){ rowptr[i0+2]=run; deg_cur[i0+2]=run; inv_deg[i0+2]=1.0f/(float)max(v2,1); run+=v2; }
  if(i0+3 < n){ rowptr[i0+3]=run; deg_cur[i0+3]=run; inv_deg[i0+3]=1.0f/(float)max(v3,1); run+=v3; }
  if(blockIdx.x == gridDim.x-1 && tid == 0) rowptr[n] = s2[1];
}

__global__ void k_fill(const int* __restrict__ src, const int* __restrict__ dst,
                       int* __restrict__ cursor, int* __restrict__ col, int e_count){
  int e = blockIdx.x*blockDim.x + threadIdx.x;
  if(e < e_count){
    int pos = atomicAdd(&cursor[src[e]], 1);
    col[pos] = dst[e];
  }
}

// ---------------- fused prep: embW1 | B-fragments | graph offsets ----------------
__global__ __launch_bounds__(256) void k_prep(const float* __restrict__ emb,
    const float* __restrict__ W1, const float* __restrict__ W2,
    const int* __restrict__ lengths, float* __restrict__ embW1,
    short* __restrict__ bW1hi, short* __restrict__ bW1lo,
    short* __restrict__ bW2hi, short* __restrict__ bW2lo, int* __restrict__ goff){
  int b = blockIdx.x, tid = threadIdx.x;
  if(b < 128){
    if(tid < 64){
      float s = 0.f;
      #pragma unroll
      for(int k=0;k<32;k++) s += emb[b*32+k] * W1[k*64+tid];
      embW1[b*64+tid] = s;
    }
  } else if(b < 152){
    int e = (b-128)*256 + tid;          // 0..6143
    {
      int i=e&7, l=(e>>3)&63, t=(e>>9)&3, kc=e>>11;
      int k=kc*32+((l>>4)<<3)+i, c=t*16+(l&15);
      float wv = W1[(32+k)*64+c];
      short h=f2bf(wv); bW1hi[e]=h; bW1lo[e]=f2bf(wv-bf2f(h));
    }
    if(e < 4096){
      int i=e&7, l=(e>>3)&63, t=(e>>9)&3, kc=e>>11;
      int k=kc*32+((l>>4)<<3)+i, c=t*16+(l&15);
      float wv = W2[k*64+c];
      short h=f2bf(wv); bW2hi[e]=h; bW2lo[e]=f2bf(wv-bf2f(h));
    }
  } else {
    if(tid == 0){
      int s = 0;
      for(int g=0; g<NG; g++){ goff[g] = s; s += lengths[g]; }
      goff[NG] = s;
    }
  }
}

// ---------------- gemm1 (MFMA, swapped) — feat via NT loads (no L3 allocation) ----------------
// z layout: [node][cfg][64] bf16
__global__ __launch_bounds__(256) void k_gemm1(const float* __restrict__ feat,
    const float* __restrict__ embW1,
    const short* __restrict__ bW1hi, const short* __restrict__ bW1lo,
    unsigned short* __restrict__ z_all){
  __shared__ float lds_f[64*FEAT];      // 24832 B; reused as zt[64][68] bf16 in epilogue
  int tid = threadIdx.x;
  int nb = blockIdx.x * 64;
  int cfg = blockIdx.y;
  const float* gsrc = feat + ((size_t)cfg*NN + nb)*FEAT;

  if(nb + 64 <= NN){
    for(int idx = tid; idx < 1552; idx += 256){
      f32x4 v = __builtin_nontemporal_load((const f32x4*)(gsrc + idx*4));
      *(f32x4*)&lds_f[idx*4] = v;
    }
  } else {
    int nvalid = (NN - nb)*FEAT;
    for(int idx = tid; idx < 1552; idx += 256){
      int base = idx*4;
      float4 v;
      v.x = (base+0 < nvalid) ? __builtin_nontemporal_load(gsrc + base+0) : 0.f;
      v.y = (base+1 < nvalid) ? __builtin_nontemporal_load(gsrc + base+1) : 0.f;
      v.z = (base+2 < nvalid) ? __builtin_nontemporal_load(gsrc + base+2) : 0.f;
      v.w = (base+3 < nvalid) ? __builtin_nontemporal_load(gsrc + base+3) : 0.f;
      *(float4*)&lds_f[base] = v;
    }
  }
  __syncthreads();

  int w = tid >> 6, l = tid & 63;
  int node_loc = w*16 + (l & 15);
  int g = l >> 4;
  int g8 = g << 3;

  f32x4 acc[4] = {{0,0,0,0},{0,0,0,0},{0,0,0,0},{0,0,0,0}};
  #pragma unroll
  for(int kc = 0; kc < 3; kc++){
    const float* ap = &lds_f[node_loc*FEAT + 1 + g8 + kc*32];
    bf16x8 bfeat;
    #pragma unroll
    for(int i=0;i<8;i++) bfeat[i] = f2bf(ap[i]);
    #pragma unroll
    for(int t=0;t<4;t++){
      const bf16x8 ah = *(const bf16x8*)&bW1hi[((kc*4 + t)*64 + l)*8];
      const bf16x8 al = *(const bf16x8*)&bW1lo[((kc*4 + t)*64 + l)*8];
      acc[t] = __builtin_amdgcn_mfma_f32_16x16x32_bf16(ah, bfeat, acc[t], 0,0,0);
      acc[t] = __builtin_amdgcn_mfma_f32_16x16x32_bf16(al, bfeat, acc[t], 0,0,0);
    }
  }
  // lane's 16 results: features t*16+g*4..+3 of node node_loc
  int myop = (int)lds_f[node_loc*FEAT];
  __syncthreads();                      // all lds_f reads done; reuse as zt
  unsigned short* zt = (unsigned short*)lds_f;   // [64][68]
  #pragma unroll
  for(int t=0;t<4;t++){
    int f0 = t*16 + (g<<2);
    const float4 e = *(const float4*)&embW1[myop*64 + f0];
    ushort4 pk;
    pk.x = (unsigned short)f2bf(acc[t][0] + e.x);
    pk.y = (unsigned short)f2bf(acc[t][1] + e.y);
    pk.z = (unsigned short)f2bf(acc[t][2] + e.z);
    pk.w = (unsigned short)f2bf(acc[t][3] + e.w);
    *(ushort4*)&zt[node_loc*68 + f0] = pk;
  }
  __syncthreads();
  // coalesced store: 64 rows x 128B (normal caching — gather1 reuses z 4x)
  unsigned short* zbase = z_all + ((size_t)nb*NCFG + cfg)*64;
  #pragma unroll
  for(int it = 0; it < 4; it++){
    int idx = it*256 + tid;             // 0..1023
    int row = idx >> 4;
    int cg  = (idx & 15) << 2;          // ushort offset (8B chunks)
    if(nb + row < NN)
      *(uint2*)(zbase + (size_t)row*NCFG*64 + cg) = *(const uint2*)&zt[row*68 + cg];
  }
}

// ---------------- gather1: h[n][c] = relu(inv*sum_nb z[nb][c] + b1), 4-chain ILP ----------------
__global__ __launch_bounds__(256) void k_gather1(const int* __restrict__ rowptr,
    const int* __restrict__ col, const float* __restrict__ inv_deg,
    const unsigned short* __restrict__ z_all, const float* __restrict__ b1,
    unsigned short* __restrict__ h_all){
  int tid = threadIdx.x, lane = tid & 63;
  int n = (blockIdx.x << 2) + (tid >> 6);
  if(n >= NN) return;
  int sub = lane & 7;
  const unsigned short* zl = z_all + lane*8;
  int kb = rowptr[n], ke = rowptr[n+1];
  float a0[8]={0,0,0,0,0,0,0,0}, a1[8]={0,0,0,0,0,0,0,0};
  float a2[8]={0,0,0,0,0,0,0,0}, a3[8]={0,0,0,0,0,0,0,0};
  int k = kb;
  for(; k+4 <= ke; k += 4){
    int d0=col[k], d1=col[k+1], d2=col[k+2], d3=col[k+3];
    const bf16x8 v0 = *(const bf16x8*)(zl + (size_t)d0*512);
    const bf16x8 v1 = *(const bf16x8*)(zl + (size_t)d1*512);
    const bf16x8 v2 = *(const bf16x8*)(zl + (size_t)d2*512);
    const bf16x8 v3 = *(const bf16x8*)(zl + (size_t)d3*512);
    #pragma unroll
    for(int i=0;i<8;i++){
      a0[i] += bf2f(v0[i]); a1[i] += bf2f(v1[i]);
      a2[i] += bf2f(v2[i]); a3[i] += bf2f(v3[i]);
    }
  }
  for(; k < ke; k++){
    int d = col[k];
    const bf16x8 v = *(const bf16x8*)(zl + (size_t)d*512);
    #pragma unroll
    for(int i=0;i<8;i++) a0[i] += bf2f(v[i]);
  }
  float inv = inv_deg[n];
  const float4 bA = *(const float4*)(b1 + sub*8);
  const float4 bB = *(const float4*)(b1 + sub*8 + 4);
  float bv[8] = {bA.x,bA.y,bA.z,bA.w,bB.x,bB.y,bB.z,bB.w};
  bf16x8 o;
  #pragma unroll
  for(int i=0;i<8;i++){
    float acc = (a0[i]+a1[i]) + (a2[i]+a3[i]);
    o[i] = f2bf(fmaxf(fmaf(acc, inv, bv[i]), 0.f));
  }
  *(bf16x8*)(h_all + (size_t)n*512 + lane*8) = o;
}

// ---------------- gather2W: r = |relu((mean_agg h) @ W2 + b2) . Wp + bp| ----------------
__global__ __launch_bounds__(256) void k_gather2W(const int* __restrict__ rowptr,
    const int* __restrict__ col, const float* __restrict__ inv_deg,
    const unsigned short* __restrict__ h_all,
    const short* __restrict__ bW2hi, const short* __restrict__ bW2lo,
    const float* __restrict__ b2, const float* __restrict__ Wp,
    const float* __restrict__ bp, float* __restrict__ r_all){
  __shared__ unsigned short V[128][68];   // row = node_local*8 + cfg
  int tid = threadIdx.x, lane = tid & 63, w = tid >> 6;
  int nb = blockIdx.x * 16;
  int cfg = lane >> 3, sub = lane & 7;
  const unsigned short* hl = h_all + lane*8;

  for(int i = 0; i < 4; i++){
    int nl = w*4 + i;
    int n = nb + nl;
    int kb = rowptr[n], ke = rowptr[n+1];
    float a0[8]={0,0,0,0,0,0,0,0}, a1[8]={0,0,0,0,0,0,0,0};
    float a2[8]={0,0,0,0,0,0,0,0}, a3[8]={0,0,0,0,0,0,0,0};
    int k = kb;
    for(; k+4 <= ke; k += 4){
      int d0=col[k], d1=col[k+1], d2=col[k+2], d3=col[k+3];
      const bf16x8 v0 = *(const bf16x8*)(hl + (size_t)d0*512);
      const bf16x8 v1 = *(const bf16x8*)(hl + (size_t)d1*512);
      const bf16x8 v2 = *(const bf16x8*)(hl + (size_t)d2*512);
      const bf16x8 v3 = *(const bf16x8*)(hl + (size_t)d3*512);
      #pragma unroll
      for(int j=0;j<8;j++){
        a0[j] += bf2f(v0[j]); a1[j] += bf2f(v1[j]);
        a2[j] += bf2f(v2[j]); a3[j] += bf2f(v3[j]);
      }
    }
    for(; k < ke; k++){
      int d = col[k];
      const bf16x8 v = *(const bf16x8*)(hl + (size_t)d*512);
      #pragma unroll
      for(int j=0;j<8;j++) a0[j] += bf2f(v[j]);
    }
    float inv = inv_deg[n];
    bf16x8 o;
    #pragma unroll
    for(int j=0;j<8;j++){
      float acc = (a0[j]+a1[j]) + (a2[j]+a3[j]);
      o[j] = f2bf(acc * inv);
    }
    *(bf16x8*)&V[nl*8 + cfg][sub*8] = o;
  }
  __syncthreads();

  float bp0 = bp[0];
  int cb = lane & 15;
  int koff = (lane >> 4) << 3;
  #pragma unroll
  for(int at = 0; at < 2; at++){
    int tile = w*2 + at;                 // 0..7
    int trow = tile*16 + cb;
    f32x4 acc[4] = {{0,0,0,0},{0,0,0,0},{0,0,0,0},{0,0,0,0}};
    #pragma unroll
    for(int kc = 0; kc < 2; kc++){
      const bf16x8 a = *(const bf16x8*)&V[trow][kc*32 + koff];
      #pragma unroll
      for(int t=0;t<4;t++){
        const bf16x8 bh = *(const bf16x8*)&bW2hi[((kc*4+t)*64 + lane)*8];
        const bf16x8 bl = *(const bf16x8*)&bW2lo[((kc*4+t)*64 + lane)*8];
        acc[t] = __builtin_amdgcn_mfma_f32_16x16x32_bf16(a, bh, acc[t], 0,0,0);
        acc[t] = __builtin_amdgcn_mfma_f32_16x16x32_bf16(a, bl, acc[t], 0,0,0);
      }
    }
    float part[4];
    #pragma unroll
    for(int j=0;j<4;j++){
      float p = 0.f;
      #pragma unroll
      for(int t=0;t<4;t++){
        int c = t*16 + cb;
        p += fmaxf(acc[t][j] + b2[c], 0.f) * Wp[c];
      }
      part[j] = p;
    }
    #pragma unroll
    for(int off=1; off<16; off<<=1){
      #pragma unroll
      for(int j=0;j<4;j++) part[j] += __shfl_xor(part[j], off, 64);
    }
    if(cb == 0){
      #pragma unroll
      for(int j=0;j<4;j++){
        int row = tile*16 + ((lane>>4)<<2) + j;   // 0..127 within block
        int node = nb + (row >> 3);
        int cfgo = row & 7;
        r_all[(size_t)cfgo*NN + node] = fabsf(part[j] + bp0);
      }
    }
  }
}

// ---------------- pool ----------------
__global__ __launch_bounds__(256) void k_pool(const float* __restrict__ r_all,
    const int* __restrict__ off, float* __restrict__ out){
  __shared__ float red[256];
  int b = blockIdx.x;               // b = g*8 + c
  int g = b >> 3, c = b & 7;
  int lo = off[g], hi = off[g+1];
  float s = 0.f;
  for(int i = lo + (int)threadIdx.x; i < hi; i += 256) s += r_all[(size_t)c*NN + i];
  red[threadIdx.x] = s;
  __syncthreads();
  for(int w=128; w>0; w>>=1){
    if((int)threadIdx.x < w) red[threadIdx.x] += red[threadIdx.x + w];
    __syncthreads();
  }
  if(threadIdx.x == 0) out[b] = red[0];
}

extern "C" void kernel_launch(void* const* d_in, const int* in_sizes, int n_in,
                              void* d_out, int out_size, void* d_ws, size_t ws_size,
                              hipStream_t stream){
  (void)in_sizes; (void)n_in; (void)out_size; (void)ws_size;
  const float* feat = (const float*)d_in[0];
  const int*   eidx = (const int*)d_in[1];
  const int*   lens = (const int*)d_in[2];
  const float* emb  = (const float*)d_in[3];
  const float* W1   = (const float*)d_in[4];
  const float* b1   = (const float*)d_in[5];
  const float* W2   = (const float*)d_in[6];
  const float* b2   = (const float*)d_in[7];
  const float* Wp   = (const float*)d_in[8];
  const float* bp   = (const float*)d_in[9];
  float* out = (float*)d_out;
  const int* src = eidx;
  const int* dst = eidx + NE;

  char* ws = (char*)d_ws;
  size_t o = 0;
  auto alloc = [&](size_t bytes)->char*{ char* p = ws + o; o = (o + bytes + 255) & ~(size_t)255; return p; };
  int*   rowptr  = (int*)  alloc((NN+1)*4);
  int*   cursor  = (int*)  alloc((size_t)NN*4);
  int*   colx    = (int*)  alloc((size_t)NE*4);
  float* invd    = (float*)alloc((size_t)NN*4);
  int*   goff    = (int*)  alloc((NG+1)*4);
  int*   spart   = (int*)  alloc(SCAN_BLOCKS*4);
  float* eW1     = (float*)alloc(128*64*4);
  short* bW1hi   = (short*)alloc(3*4*64*8*2);
  short* bW1lo   = (short*)alloc(3*4*64*8*2);
  short* bW2hi   = (short*)alloc(2*4*64*8*2);
  short* bW2lo   = (short*)alloc(2*4*64*8*2);
  float* r_all   = (float*)alloc((size_t)NCFG*NN*4);
  unsigned short* z_all = (unsigned short*)alloc((size_t)NN*NCFG*64*2);  // 102.4 MB, [node][cfg][64]
  unsigned short* h_all = (unsigned short*)alloc((size_t)NN*NCFG*64*2);  // 102.4 MB

  hipMemsetAsync(cursor, 0, (size_t)NN*4, stream);
  k_hist  <<<(NE+255)/256, 256, 0, stream>>>(src, cursor, NE);
  k_scanA <<<SCAN_BLOCKS, 1024, 0, stream>>>(cursor, spart, NN);
  k_scanC <<<SCAN_BLOCKS, 1024, 0, stream>>>(cursor, spart, rowptr, invd, NN);
  k_fill  <<<(NE+255)/256, 256, 0, stream>>>(src, dst, cursor, colx, NE);
  k_prep  <<<153, 256, 0, stream>>>(emb, W1, W2, lens, eW1, bW1hi, bW1lo, bW2hi, bW2lo, goff);

  dim3 ggemm((NN+63)/64, NCFG);
  k_gemm1   <<<ggemm, 256, 0, stream>>>(feat, eW1, bW1hi, bW1lo, z_all);
  k_gather1 <<<(NN+3)/4, 256, 0, stream>>>(rowptr, colx, invd, z_all, b1, h_all);
  k_gather2W<<<NN/16, 256, 0, stream>>>(rowptr, colx, invd, h_all, bW2hi, bW2lo, b2, Wp, bp, r_all);
  k_pool<<<NCFG*NG, 256, 0, stream>>>(r_all, goff, out);
}

// Round 12
// 354.836 us; speedup vs baseline: 1.4820x; 1.0071x over previous
//
#include <hip/hip_runtime.h>

#define NCFG 8
#define NN 100000
#define NE 400000
#define NG 10
#define FEAT 97
#define SCAN_BLOCKS 25   // ceil(NN/4096)

typedef __attribute__((ext_vector_type(8))) short bf16x8;
typedef __attribute__((ext_vector_type(4))) float f32x4;

__device__ inline short f2bf(float x){
  unsigned u = __float_as_uint(x);
  unsigned r = u + 0x7FFFu + ((u >> 16) & 1u);
  return (short)(r >> 16);
}
__device__ inline float bf2f(short h){
  return __uint_as_float(((unsigned)(unsigned short)h) << 16);
}

// ---------------- CSR build ----------------
__global__ void k_hist(const int* __restrict__ src, int* __restrict__ deg, int e_count){
  int e = blockIdx.x*blockDim.x + threadIdx.x;
  if(e < e_count) atomicAdd(&deg[src[e]], 1);
}

__global__ __launch_bounds__(1024) void k_scanA(const int* __restrict__ deg,
    int* __restrict__ partial, int n){
  __shared__ int ws[16];
  int tid = threadIdx.x;
  int i0 = blockIdx.x*4096 + tid*4;
  int s = 0;
  #pragma unroll
  for(int i=0;i<4;i++) if(i0+i < n) s += deg[i0+i];
  #pragma unroll
  for(int off=1; off<64; off<<=1) s += __shfl_xor(s, off, 64);
  if((tid & 63) == 0) ws[tid >> 6] = s;
  __syncthreads();
  if(tid < 16){
    int v = ws[tid];
    #pragma unroll
    for(int off=1; off<16; off<<=1) v += __shfl_xor(v, off, 16);
    if(tid == 0) partial[blockIdx.x] = v;
  }
}

// local scan + inline prefix of partials
__global__ __launch_bounds__(1024) void k_scanC(int* __restrict__ deg_cur,
    const int* __restrict__ partial, int* __restrict__ rowptr,
    float* __restrict__ inv_deg, int n){
  __shared__ int wsum[16];
  __shared__ int s2[2];            // [0]=block offset, [1]=grand total
  int tid = threadIdx.x, lane = tid & 63, w = tid >> 6;
  if(tid < 64){
    int pv  = (lane < SCAN_BLOCKS) ? partial[lane] : 0;
    int pre = (lane < (int)blockIdx.x) ? pv : 0;
    #pragma unroll
    for(int off=1; off<32; off<<=1){
      pv  += __shfl_xor(pv,  off, 64);
      pre += __shfl_xor(pre, off, 64);
    }
    if(lane == 0){ s2[0] = pre; s2[1] = pv; }
  }
  int i0 = blockIdx.x*4096 + tid*4;
  int v0 = (i0+0 < n) ? deg_cur[i0+0] : 0;
  int v1 = (i0+1 < n) ? deg_cur[i0+1] : 0;
  int v2 = (i0+2 < n) ? deg_cur[i0+2] : 0;
  int v3 = (i0+3 < n) ? deg_cur[i0+3] : 0;
  int s = v0+v1+v2+v3;
  int x = s;
  #pragma unroll
  for(int off=1; off<64; off<<=1){
    int t = __shfl_up(x, off, 64);
    if(lane >= off) x += t;
  }
  if(lane == 63) wsum[w] = x;
  __syncthreads();
  if(w == 0){
    int y = (lane < 16) ? wsum[lane] : 0;
    #pragma unroll
    for(int off=1; off<16; off<<=1){
      int t = __shfl_up(y, off, 64);
      if(lane >= off) y += t;
    }
    if(lane < 16) wsum[lane] = y;
  }
  __syncthreads();
  int waveoff = (w > 0) ? wsum[w-1] : 0;
  int run = s2[0] + waveoff + (x - s);
  if(i0+0 < n){ rowptr[i0+0]=run; deg_cur[i0+0]=run; inv_deg[i0+0]=1.0f/(float)max(v0,1); run+=v0; }
  if(i0+1 < n){ rowptr[i0+1]=run; deg_cur[i0+1]=run; inv_deg[i0+1]=1.0f/(float)max(v1,1); run+=v1; }
  if(i0+2 < n){ rowptr[i0+2]=run; deg_cur[i0+2]=run; inv_deg[i0+2]=1.0f/(float)max(v2,1); run+=v2; }
  if(i0+3 < n){ rowptr[i0+3]=run; deg_cur[i0+3]=run; inv_deg[i0+3]=1.0f/(float)max(v3,1); run+=v3; }
  if(blockIdx.x == gridDim.x-1 && tid == 0) rowptr[n] = s2[1];
}

__global__ void k_fill(const int* __restrict__ src, const int* __restrict__ dst,
                       int* __restrict__ cursor, int* __restrict__ col, int e_count){
  int e = blockIdx.x*blockDim.x + threadIdx.x;
  if(e < e_count){
    int pos = atomicAdd(&cursor[src[e]], 1);
    col[pos] = dst[e];
  }
}

// ---------------- fused prep: embW1 | B-fragments | graph offsets ----------------
__global__ __launch_bounds__(256) void k_prep(const float* __restrict__ emb,
    const float* __restrict__ W1, const float* __restrict__ W2,
    const int* __restrict__ lengths, float* __restrict__ embW1,
    short* __restrict__ bW1hi, short* __restrict__ bW1lo,
    short* __restrict__ bW2hi, short* __restrict__ bW2lo, int* __restrict__ goff){
  int b = blockIdx.x, tid = threadIdx.x;
  if(b < 128){
    if(tid < 64){
      float s = 0.f;
      #pragma unroll
      for(int k=0;k<32;k++) s += emb[b*32+k] * W1[k*64+tid];
      embW1[b*64+tid] = s;
    }
  } else if(b < 152){
    int e = (b-128)*256 + tid;          // 0..6143
    {
      int i=e&7, l=(e>>3)&63, t=(e>>9)&3, kc=e>>11;
      int k=kc*32+((l>>4)<<3)+i, c=t*16+(l&15);
      float wv = W1[(32+k)*64+c];
      short h=f2bf(wv); bW1hi[e]=h; bW1lo[e]=f2bf(wv-bf2f(h));
    }
    if(e < 4096){
      int i=e&7, l=(e>>3)&63, t=(e>>9)&3, kc=e>>11;
      int k=kc*32+((l>>4)<<3)+i, c=t*16+(l&15);
      float wv = W2[k*64+c];
      short h=f2bf(wv); bW2hi[e]=h; bW2lo[e]=f2bf(wv-bf2f(h));
    }
  } else {
    if(tid == 0){
      int s = 0;
      for(int g=0; g<NG; g++){ goff[g] = s; s += lengths[g]; }
      goff[NG] = s;
    }
  }
}

// ---------------- gemm1 (MFMA, swapped) — feat via NT loads ----------------
// z layout: [node][cfg][64] bf16
__global__ __launch_bounds__(256) void k_gemm1(const float* __restrict__ feat,
    const float* __restrict__ embW1,
    const short* __restrict__ bW1hi, const short* __restrict__ bW1lo,
    unsigned short* __restrict__ z_all){
  __shared__ float lds_f[64*FEAT];      // 24832 B; reused as zt[64][68] bf16 in epilogue
  int tid = threadIdx.x;
  int nb = blockIdx.x * 64;
  int cfg = blockIdx.y;
  const float* gsrc = feat + ((size_t)cfg*NN + nb)*FEAT;

  if(nb + 64 <= NN){
    for(int idx = tid; idx < 1552; idx += 256){
      f32x4 v = __builtin_nontemporal_load((const f32x4*)(gsrc + idx*4));
      *(f32x4*)&lds_f[idx*4] = v;
    }
  } else {
    int nvalid = (NN - nb)*FEAT;
    for(int idx = tid; idx < 1552; idx += 256){
      int base = idx*4;
      float4 v;
      v.x = (base+0 < nvalid) ? __builtin_nontemporal_load(gsrc + base+0) : 0.f;
      v.y = (base+1 < nvalid) ? __builtin_nontemporal_load(gsrc + base+1) : 0.f;
      v.z = (base+2 < nvalid) ? __builtin_nontemporal_load(gsrc + base+2) : 0.f;
      v.w = (base+3 < nvalid) ? __builtin_nontemporal_load(gsrc + base+3) : 0.f;
      *(float4*)&lds_f[base] = v;
    }
  }
  __syncthreads();

  int w = tid >> 6, l = tid & 63;
  int node_loc = w*16 + (l & 15);
  int g = l >> 4;
  int g8 = g << 3;

  f32x4 acc[4] = {{0,0,0,0},{0,0,0,0},{0,0,0,0},{0,0,0,0}};
  #pragma unroll
  for(int kc = 0; kc < 3; kc++){
    const float* ap = &lds_f[node_loc*FEAT + 1 + g8 + kc*32];
    bf16x8 bfeat;
    #pragma unroll
    for(int i=0;i<8;i++) bfeat[i] = f2bf(ap[i]);
    #pragma unroll
    for(int t=0;t<4;t++){
      const bf16x8 ah = *(const bf16x8*)&bW1hi[((kc*4 + t)*64 + l)*8];
      const bf16x8 al = *(const bf16x8*)&bW1lo[((kc*4 + t)*64 + l)*8];
      acc[t] = __builtin_amdgcn_mfma_f32_16x16x32_bf16(ah, bfeat, acc[t], 0,0,0);
      acc[t] = __builtin_amdgcn_mfma_f32_16x16x32_bf16(al, bfeat, acc[t], 0,0,0);
    }
  }
  int myop = (int)lds_f[node_loc*FEAT];
  __syncthreads();                      // all lds_f reads done; reuse as zt
  unsigned short* zt = (unsigned short*)lds_f;   // [64][68]
  #pragma unroll
  for(int t=0;t<4;t++){
    int f0 = t*16 + (g<<2);
    const float4 e = *(const float4*)&embW1[myop*64 + f0];
    ushort4 pk;
    pk.x = (unsigned short)f2bf(acc[t][0] + e.x);
    pk.y = (unsigned short)f2bf(acc[t][1] + e.y);
    pk.z = (unsigned short)f2bf(acc[t][2] + e.z);
    pk.w = (unsigned short)f2bf(acc[t][3] + e.w);
    *(ushort4*)&zt[node_loc*68 + f0] = pk;
  }
  __syncthreads();
  unsigned short* zbase = z_all + ((size_t)nb*NCFG + cfg)*64;
  #pragma unroll
  for(int it = 0; it < 4; it++){
    int idx = it*256 + tid;             // 0..1023
    int row = idx >> 4;
    int cg  = (idx & 15) << 2;
    if(nb + row < NN)
      *(uint2*)(zbase + (size_t)row*NCFG*64 + cg) = *(const uint2*)&zt[row*68 + cg];
  }
}

// ---------------- gather1: wave interleaves TWO nodes' edge walks ----------------
__global__ __launch_bounds__(256) void k_gather1(const int* __restrict__ rowptr,
    const int* __restrict__ col, const float* __restrict__ inv_deg,
    const unsigned short* __restrict__ z_all, const float* __restrict__ b1,
    unsigned short* __restrict__ h_all){
  int tid = threadIdx.x, lane = tid & 63;
  int n0 = (blockIdx.x << 3) + ((tid >> 6) << 1);   // wave -> nodes n0, n0+1
  if(n0 >= NN) return;
  bool two = (n0 + 1 < NN);
  int sub = lane & 7;
  const unsigned short* zl = z_all + lane*8;
  int kb0 = rowptr[n0], ke0 = rowptr[n0+1];
  int ke1 = two ? rowptr[n0+2] : ke0;               // kb1 == ke0 (contiguous CSR)
  int dg0 = ke0 - kb0, dg1 = ke1 - ke0;
  float a0[8]={0,0,0,0,0,0,0,0}, a1[8]={0,0,0,0,0,0,0,0};
  int m = min(dg0, dg1);
  int i = 0;
  for(; i < m; i++){                                 // 2 independent chains
    int d0 = col[kb0 + i], d1 = col[ke0 + i];
    const bf16x8 v0 = *(const bf16x8*)(zl + (size_t)d0*512);
    const bf16x8 v1 = *(const bf16x8*)(zl + (size_t)d1*512);
    #pragma unroll
    for(int j=0;j<8;j++){ a0[j] += bf2f(v0[j]); a1[j] += bf2f(v1[j]); }
  }
  for(; i < dg0; i++){
    int d = col[kb0 + i];
    const bf16x8 v = *(const bf16x8*)(zl + (size_t)d*512);
    #pragma unroll
    for(int j=0;j<8;j++) a0[j] += bf2f(v[j]);
  }
  for(i = m; i < dg1; i++){
    int d = col[ke0 + i];
    const bf16x8 v = *(const bf16x8*)(zl + (size_t)d*512);
    #pragma unroll
    for(int j=0;j<8;j++) a1[j] += bf2f(v[j]);
  }
  const float4 bA = *(const float4*)(b1 + sub*8);
  const float4 bB = *(const float4*)(b1 + sub*8 + 4);
  float bv[8] = {bA.x,bA.y,bA.z,bA.w,bB.x,bB.y,bB.z,bB.w};
  {
    float inv = inv_deg[n0];
    bf16x8 o;
    #pragma unroll
    for(int j=0;j<8;j++) o[j] = f2bf(fmaxf(fmaf(a0[j], inv, bv[j]), 0.f));
    *(bf16x8*)(h_all + (size_t)n0*512 + lane*8) = o;
  }
  if(two){
    float inv = inv_deg[n0+1];
    bf16x8 o;
    #pragma unroll
    for(int j=0;j<8;j++) o[j] = f2bf(fmaxf(fmaf(a1[j], inv, bv[j]), 0.f));
    *(bf16x8*)(h_all + (size_t)(n0+1)*512 + lane*8) = o;
  }
}

// ---------------- gather2W: phase1 agg (2-node interleaved pairs) -> LDS, phase2 MFMA ----------------
__global__ __launch_bounds__(256) void k_gather2W(const int* __restrict__ rowptr,
    const int* __restrict__ col, const float* __restrict__ inv_deg,
    const unsigned short* __restrict__ h_all,
    const short* __restrict__ bW2hi, const short* __restrict__ bW2lo,
    const float* __restrict__ b2, const float* __restrict__ Wp,
    const float* __restrict__ bp, float* __restrict__ r_all){
  __shared__ unsigned short V[128][68];   // row = node_local*8 + cfg
  int tid = threadIdx.x, lane = tid & 63, w = tid >> 6;
  int nb = blockIdx.x * 16;               // NN % 16 == 0: all nodes valid
  int cfg = lane >> 3, sub = lane & 7;
  const unsigned short* hl = h_all + lane*8;

  #pragma unroll
  for(int pr = 0; pr < 2; pr++){
    int nlA = w*4 + pr*2;
    int nA = nb + nlA;                    // pair nA, nA+1 (contiguous CSR)
    int kbA = rowptr[nA], keA = rowptr[nA+1], keB = rowptr[nA+2];
    int dgA = keA - kbA, dgB = keB - keA;
    float a0[8]={0,0,0,0,0,0,0,0}, a1[8]={0,0,0,0,0,0,0,0};
    int m = min(dgA, dgB);
    int i = 0;
    for(; i < m; i++){
      int d0 = col[kbA + i], d1 = col[keA + i];
      const bf16x8 v0 = *(const bf16x8*)(hl + (size_t)d0*512);
      const bf16x8 v1 = *(const bf16x8*)(hl + (size_t)d1*512);
      #pragma unroll
      for(int j=0;j<8;j++){ a0[j] += bf2f(v0[j]); a1[j] += bf2f(v1[j]); }
    }
    for(; i < dgA; i++){
      int d = col[kbA + i];
      const bf16x8 v = *(const bf16x8*)(hl + (size_t)d*512);
      #pragma unroll
      for(int j=0;j<8;j++) a0[j] += bf2f(v[j]);
    }
    for(i = m; i < dgB; i++){
      int d = col[keA + i];
      const bf16x8 v = *(const bf16x8*)(hl + (size_t)d*512);
      #pragma unroll
      for(int j=0;j<8;j++) a1[j] += bf2f(v[j]);
    }
    {
      float inv = inv_deg[nA];
      bf16x8 o;
      #pragma unroll
      for(int j=0;j<8;j++) o[j] = f2bf(a0[j] * inv);
      *(bf16x8*)&V[nlA*8 + cfg][sub*8] = o;
    }
    {
      float inv = inv_deg[nA+1];
      bf16x8 o;
      #pragma unroll
      for(int j=0;j<8;j++) o[j] = f2bf(a1[j] * inv);
      *(bf16x8*)&V[(nlA+1)*8 + cfg][sub*8] = o;
    }
  }
  __syncthreads();

  float bp0 = bp[0];
  int cb = lane & 15;
  int koff = (lane >> 4) << 3;
  #pragma unroll
  for(int at = 0; at < 2; at++){
    int tile = w*2 + at;                 // 0..7
    int trow = tile*16 + cb;
    f32x4 acc[4] = {{0,0,0,0},{0,0,0,0},{0,0,0,0},{0,0,0,0}};
    #pragma unroll
    for(int kc = 0; kc < 2; kc++){
      const bf16x8 a = *(const bf16x8*)&V[trow][kc*32 + koff];
      #pragma unroll
      for(int t=0;t<4;t++){
        const bf16x8 bh = *(const bf16x8*)&bW2hi[((kc*4+t)*64 + lane)*8];
        const bf16x8 bl = *(const bf16x8*)&bW2lo[((kc*4+t)*64 + lane)*8];
        acc[t] = __builtin_amdgcn_mfma_f32_16x16x32_bf16(a, bh, acc[t], 0,0,0);
        acc[t] = __builtin_amdgcn_mfma_f32_16x16x32_bf16(a, bl, acc[t], 0,0,0);
      }
    }
    float part[4];
    #pragma unroll
    for(int j=0;j<4;j++){
      float p = 0.f;
      #pragma unroll
      for(int t=0;t<4;t++){
        int c = t*16 + cb;
        p += fmaxf(acc[t][j] + b2[c], 0.f) * Wp[c];
      }
      part[j] = p;
    }
    #pragma unroll
    for(int off=1; off<16; off<<=1){
      #pragma unroll
      for(int j=0;j<4;j++) part[j] += __shfl_xor(part[j], off, 64);
    }
    if(cb == 0){
      #pragma unroll
      for(int j=0;j<4;j++){
        int row = tile*16 + ((lane>>4)<<2) + j;   // 0..127 within block
        int node = nb + (row >> 3);
        int cfgo = row & 7;
        r_all[(size_t)cfgo*NN + node] = fabsf(part[j] + bp0);
      }
    }
  }
}

// ---------------- pool ----------------
__global__ __launch_bounds__(256) void k_pool(const float* __restrict__ r_all,
    const int* __restrict__ off, float* __restrict__ out){
  __shared__ float red[256];
  int b = blockIdx.x;               // b = g*8 + c
  int g = b >> 3, c = b & 7;
  int lo = off[g], hi = off[g+1];
  float s = 0.f;
  for(int i = lo + (int)threadIdx.x; i < hi; i += 256) s += r_all[(size_t)c*NN + i];
  red[threadIdx.x] = s;
  __syncthreads();
  for(int w=128; w>0; w>>=1){
    if((int)threadIdx.x < w) red[threadIdx.x] += red[threadIdx.x + w];
    __syncthreads();
  }
  if(threadIdx.x == 0) out[b] = red[0];
}

extern "C" void kernel_launch(void* const* d_in, const int* in_sizes, int n_in,
                              void* d_out, int out_size, void* d_ws, size_t ws_size,
                              hipStream_t stream){
  (void)in_sizes; (void)n_in; (void)out_size; (void)ws_size;
  const float* feat = (const float*)d_in[0];
  const int*   eidx = (const int*)d_in[1];
  const int*   lens = (const int*)d_in[2];
  const float* emb  = (const float*)d_in[3];
  const float* W1   = (const float*)d_in[4];
  const float* b1   = (const float*)d_in[5];
  const float* W2   = (const float*)d_in[6];
  const float* b2   = (const float*)d_in[7];
  const float* Wp   = (const float*)d_in[8];
  const float* bp   = (const float*)d_in[9];
  float* out = (float*)d_out;
  const int* src = eidx;
  const int* dst = eidx + NE;

  char* ws = (char*)d_ws;
  size_t o = 0;
  auto alloc = [&](size_t bytes)->char*{ char* p = ws + o; o = (o + bytes + 255) & ~(size_t)255; return p; };
  int*   rowptr  = (int*)  alloc((NN+1)*4);
  int*   cursor  = (int*)  alloc((size_t)NN*4);
  int*   colx    = (int*)  alloc((size_t)NE*4);
  float* invd    = (float*)alloc((size_t)NN*4);
  int*   goff    = (int*)  alloc((NG+1)*4);
  int*   spart   = (int*)  alloc(SCAN_BLOCKS*4);
  float* eW1     = (float*)alloc(128*64*4);
  short* bW1hi   = (short*)alloc(3*4*64*8*2);
  short* bW1lo   = (short*)alloc(3*4*64*8*2);
  short* bW2hi   = (short*)alloc(2*4*64*8*2);
  short* bW2lo   = (short*)alloc(2*4*64*8*2);
  float* r_all   = (float*)alloc((size_t)NCFG*NN*4);
  unsigned short* z_all = (unsigned short*)alloc((size_t)NN*NCFG*64*2);  // 102.4 MB, [node][cfg][64]
  unsigned short* h_all = (unsigned short*)alloc((size_t)NN*NCFG*64*2);  // 102.4 MB

  hipMemsetAsync(cursor, 0, (size_t)NN*4, stream);
  k_hist  <<<(NE+255)/256, 256, 0, stream>>>(src, cursor, NE);
  k_scanA <<<SCAN_BLOCKS, 1024, 0, stream>>>(cursor, spart, NN);
  k_scanC <<<SCAN_BLOCKS, 1024, 0, stream>>>(cursor, spart, rowptr, invd, NN);
  k_fill  <<<(NE+255)/256, 256, 0, stream>>>(src, dst, cursor, colx, NE);
  k_prep  <<<153, 256, 0, stream>>>(emb, W1, W2, lens, eW1, bW1hi, bW1lo, bW2hi, bW2lo, goff);

  dim3 ggemm((NN+63)/64, NCFG);
  k_gemm1   <<<ggemm, 256, 0, stream>>>(feat, eW1, bW1hi, bW1lo, z_all);
  k_gather1 <<<(NN+7)/8, 256, 0, stream>>>(rowptr, colx, invd, z_all, b1, h_all);
  k_gather2W<<<NN/16, 256, 0, stream>>>(rowptr, colx, invd, h_all, bW2hi, bW2lo, b2, Wp, bp, r_all);
  k_pool<<<NCFG*NG, 256, 0, stream>>>(r_all, goff, out);
}